// Round 13
// baseline (407.865 us; speedup 1.0000x reference)
//
#include <hip/hip_runtime.h>
#include <hip/hip_bf16.h>
#include <stdint.h>

constexpr int N     = 100000;
constexpr int E     = 1600000;
constexpr int ETOT  = E + N;
constexpr int F     = 256;
constexpr int H     = 8;
constexpr int C     = 16;
constexpr int HC    = H * C;      // 128
constexpr int NCLS  = 16;
constexpr float NEG_SLOPE = 0.2f;

constexpr int BSHIFT = 8;                       // 256 dsts per bucket
constexpr int NBUCK  = (N + 255) >> BSHIFT;     // 391
constexpr int BCAP   = 8192;
constexpr int TILE   = 16384;
constexpr int NTILE  = (ETOT + TILE - 1) / TILE;

typedef __attribute__((ext_vector_type(8))) short short8;
typedef __attribute__((ext_vector_type(4))) float f32x4;
typedef __attribute__((ext_vector_type(4))) unsigned int u32x4;

__device__ inline unsigned short f2bf(float f) {
    union { float f; unsigned int u; } v{f};
    unsigned int r = v.u + 0x7FFF + ((v.u >> 16) & 1);   // RNE
    return (unsigned short)(r >> 16);
}
__device__ inline float bf2f(unsigned short s) {
    union { unsigned int u; float f; } v{(unsigned int)s << 16};
    return v.f;
}

// ---------------- CSR build: LDS-staged two-level counting sort (proven chain) ----

__global__ __launch_bounds__(256) void k_bhist(const int* __restrict__ ei,
                                               int* __restrict__ bcnt) {
    __shared__ int h[NBUCK];
    for (int i = threadIdx.x; i < NBUCK; i += 256) h[i] = 0;
    __syncthreads();
    int t0 = blockIdx.x * TILE;
    int t1 = (t0 + TILE < ETOT) ? t0 + TILE : ETOT;
    for (int e = t0 + threadIdx.x; e < t1; e += 256) {
        int d = (e < E) ? ei[E + e] : (e - E);
        atomicAdd(&h[d >> BSHIFT], 1);
    }
    __syncthreads();
    for (int i = threadIdx.x; i < NBUCK; i += 256) {
        int c = h[i];
        if (c) atomicAdd(&bcnt[i], c);
    }
}

__global__ void k_bscan(const int* __restrict__ bcnt, int* __restrict__ boff,
                        int* __restrict__ bcur, int* __restrict__ off) {
    __shared__ int s[512];
    int tid = threadIdx.x;
    int v = (tid < NBUCK) ? bcnt[tid] : 0;
    s[tid] = v; __syncthreads();
    for (int ofs = 1; ofs < 512; ofs <<= 1) {
        int t = (tid >= ofs) ? s[tid - ofs] : 0;
        __syncthreads();
        s[tid] += t;
        __syncthreads();
    }
    if (tid < NBUCK) { int ex = s[tid] - v; boff[tid] = ex; bcur[tid] = ex; }
    if (tid == 0) off[N] = ETOT;
}

__global__ __launch_bounds__(256) void k_part(const int* __restrict__ ei,
                                              int* __restrict__ bcur,
                                              unsigned int* __restrict__ pairs) {
    __shared__ int h[NBUCK];
    __shared__ int base[NBUCK];
    int t0 = blockIdx.x * TILE;
    int t1 = (t0 + TILE < ETOT) ? t0 + TILE : ETOT;
    for (int i = threadIdx.x; i < NBUCK; i += 256) h[i] = 0;
    __syncthreads();
    for (int e = t0 + threadIdx.x; e < t1; e += 256) {
        int d = (e < E) ? ei[E + e] : (e - E);
        atomicAdd(&h[d >> BSHIFT], 1);
    }
    __syncthreads();
    for (int i = threadIdx.x; i < NBUCK; i += 256) {
        int c = h[i];
        base[i] = c ? atomicAdd(&bcur[i], c) : 0;
    }
    __syncthreads();
    for (int i = threadIdx.x; i < NBUCK; i += 256) h[i] = 0;
    __syncthreads();
    for (int e = t0 + threadIdx.x; e < t1; e += 256) {
        int s, d;
        if (e < E) { s = ei[e]; d = ei[E + e]; } else { s = e - E; d = s; }
        int b = d >> BSHIFT;
        int r = atomicAdd(&h[b], 1);
        pairs[base[b] + r] = ((unsigned)s << 8) | (unsigned)(d & 255);
    }
}

__global__ __launch_bounds__(256) void k_bsort(const unsigned int* __restrict__ pairs,
                                               const int* __restrict__ bcnt,
                                               const int* __restrict__ boff,
                                               int* __restrict__ csr,
                                               int* __restrict__ off) {
    __shared__ int srcs[BCAP];
    __shared__ int csrs[BCAP];
    __shared__ unsigned char dl[BCAP];
    __shared__ int hist[256];
    __shared__ int sc[256];
    int b = blockIdx.x;
    int nb = bcnt[b]; if (nb > BCAP) nb = BCAP;
    int base = boff[b];
    int dbase = b << BSHIFT;
    int ndst = (N - dbase < 256) ? (N - dbase) : 256;
    int tid = threadIdx.x;

    for (int i = tid; i < nb; i += 256) {
        unsigned int p = pairs[base + i];
        srcs[i] = (int)(p >> 8);
        dl[i] = (unsigned char)(p & 255);
    }
    hist[tid] = 0;
    __syncthreads();
    for (int i = tid; i < nb; i += 256) atomicAdd(&hist[dl[i]], 1);
    __syncthreads();
    int v = hist[tid];
    sc[tid] = v;
    __syncthreads();
    for (int ofs = 1; ofs < 256; ofs <<= 1) {
        int t = (tid >= ofs) ? sc[tid - ofs] : 0;
        __syncthreads();
        sc[tid] += t;
        __syncthreads();
    }
    int lo = sc[tid] - v;
    if (tid < ndst) off[dbase + tid] = base + lo;
    hist[tid] = lo;
    __syncthreads();
    for (int i = tid; i < nb; i += 256) {
        int r = atomicAdd(&hist[dl[i]], 1);
        csrs[r] = srcs[i];
    }
    __syncthreads();
    for (int i = tid; i < nb; i += 256) csr[base + i] = csrs[i];
}

// ---------------- weight prep: w1x rows 0..127 = bf16(W1); 128..143 = score cols

__global__ void k_w1cast(const float* __restrict__ W1, unsigned short* __restrict__ w1x) {
    int i = blockIdx.x * 256 + threadIdx.x;
    if (i < HC * F) w1x[i] = f2bf(W1[i]);
}

__global__ void k_wext(const float* __restrict__ W1,
                       const float* __restrict__ aws, const float* __restrict__ awd,
                       unsigned short* __restrict__ w1x) {
    int r = blockIdx.x;          // 0..15: 0-7 src-heads, 8-15 dst-heads
    int k = threadIdx.x;         // 0..255
    int h = r & 7;
    const float* aw = (r < 8) ? aws : awd;
    float acc = 0.f;
#pragma unroll
    for (int c = 0; c < 16; ++c)
        acc += aw[h * 16 + c] * W1[(size_t)(h * 16 + c) * F + k];
    w1x[(size_t)(128 + r) * F + k] = f2bf(acc);
}

// ---------------- gemm1: h1m = bf16(x)@bf16(W1)^T, fused att scores (cols 128-143)

__global__ __launch_bounds__(256) void k_gemm1(const float* __restrict__ x,
                                               const unsigned short* __restrict__ w1x,
                                               unsigned short* __restrict__ h1m,
                                               float* __restrict__ as1,
                                               float* __restrict__ ad1) {
    __shared__ unsigned short Ws[HC * F];  // 64KB, XOR-swizzled 16B chunks (rows 0..127)
    for (int i = threadIdx.x; i < 4096; i += 256) {
        int row = i >> 5;
        int c16 = i & 31;
        u32x4 v = ((const u32x4*)w1x)[i];
        int byte = row * 512 + ((c16 * 16) ^ ((row & 7) << 4));
        *((u32x4*)((char*)Ws + byte)) = v;
    }
    __syncthreads();

    int wid = threadIdx.x >> 6, lane = threadIdx.x & 63;
    int r16 = lane & 15, g = lane >> 4;
    int m = blockIdx.x * 64 + wid * 16 + r16;
    int mc = (m < N) ? m : (N - 1);
    const float* xr = x + (size_t)mc * F;
    const unsigned short* wext = w1x + (size_t)(128 + r16) * F;

    f32x4 acc[9];
#pragma unroll
    for (int nf = 0; nf < 9; ++nf) acc[nf] = (f32x4){0.f, 0.f, 0.f, 0.f};

#pragma unroll
    for (int kk = 0; kk < 8; ++kk) {
        f32x4 a0 = *((const f32x4*)(xr + kk * 32 + g * 8));
        f32x4 a1 = *((const f32x4*)(xr + kk * 32 + g * 8 + 4));
        short8 af;
#pragma unroll
        for (int j = 0; j < 4; ++j) {
            af[j]     = (short)f2bf(a0[j]);
            af[4 + j] = (short)f2bf(a1[j]);
        }
        int kbyte = kk * 64 + g * 16;
#pragma unroll
        for (int nf = 0; nf < 8; ++nf) {
            int row = nf * 16 + r16;
            int byte = row * 512 + (kbyte ^ ((row & 7) << 4));
            short8 bf = *((const short8*)((const char*)Ws + byte));
            acc[nf] = __builtin_amdgcn_mfma_f32_16x16x32_bf16(af, bf, acc[nf], 0, 0, 0);
        }
        short8 bfx = *((const short8*)(wext + kk * 32 + g * 8));
        acc[8] = __builtin_amdgcn_mfma_f32_16x16x32_bf16(af, bfx, acc[8], 0, 0, 0);
    }

    int orow = blockIdx.x * 64 + wid * 16 + g * 4;
#pragma unroll
    for (int j = 0; j < 4; ++j) {
        int rr = orow + j;
        if (rr >= N) continue;
        unsigned short* dst = h1m + (size_t)rr * HC + r16;
#pragma unroll
        for (int nf = 0; nf < 8; ++nf) dst[nf * 16] = f2bf(acc[nf][j]);
        float v = acc[8][j];
        if (r16 < 8) as1[rr * 8 + r16] = v;
        else         ad1[rr * 8 + (r16 - 8)] = v;
    }
}

// ---- layer 1 aggregate + fused layer-2 GEMM, grid-stride, reg-resident W2 ----
// No LDS at all: W2/b1/aw fragments read once from global (L1/L2-resident).

__global__ __launch_bounds__(256, 8) void k_agg1(const int* __restrict__ off,
                                                 const int* __restrict__ csr,
                                                 const unsigned int* __restrict__ h1w,
                                                 const float* __restrict__ as1,
                                                 const float* __restrict__ ad1,
                                                 const float* __restrict__ b1,
                                                 const float* __restrict__ W2,
                                                 const float* __restrict__ aw_s2,
                                                 const float* __restrict__ aw_d2,
                                                 unsigned short* __restrict__ h2b,
                                                 float* __restrict__ as2,
                                                 float* __restrict__ ad2) {
    int w = threadIdx.x >> 6, l = threadIdx.x & 63;
    int g  = l >> 4;            // edge slot 0..3 / class group
    int c8 = l & 15;            // channel block (8 bf16)
    int hh = c8 >> 1;           // head of this block
    unsigned int wb = (unsigned int)(c8 * 4);

    // one-time register fragments (from global; W2 is 8KB -> L1/L2 hit)
    float w2f[32];
#pragma unroll
    for (int q = 0; q < 8; ++q)
#pragma unroll
        for (int j = 0; j < 4; ++j)
            w2f[q * 4 + j] = W2[(size_t)(g * 4 + j) * HC + c8 * 8 + q];
    float b1f[8];
#pragma unroll
    for (int q = 0; q < 8; ++q) b1f[q] = b1[c8 * 8 + q];
    float awsf[4], awdf[4];
#pragma unroll
    for (int j = 0; j < 4; ++j) {
        awsf[j] = aw_s2[g * 4 + j];
        awdf[j] = aw_d2[g * 4 + j];
    }

    for (int n = blockIdx.x * 4 + w; n < N; n += gridDim.x * 4) {
        int e0 = off[n], e1 = off[n + 1];
        int deg = e1 - e0;
        float adst = ad1[n * 8 + hh];
        float den = 0.f;
        float acc[8] = {0.f, 0.f, 0.f, 0.f, 0.f, 0.f, 0.f, 0.f};

        int eb = 0;
        for (; eb + 8 <= deg; eb += 8) {
            int sA = csr[e0 + eb + g];
            int sB = csr[e0 + eb + 4 + g];
            float avA = as1[sA * 8 + hh];
            float avB = as1[sB * 8 + hh];
            unsigned int rA = (unsigned int)sA << 6;
            unsigned int rB = (unsigned int)sB << 6;
            u32x4 vA = *((const u32x4*)(h1w + rA + wb));
            u32x4 vB = *((const u32x4*)(h1w + rB + wb));
            float aA = avA + adst; aA = fmaxf(aA, aA * NEG_SLOPE);
            float aB = avB + adst; aB = fmaxf(aB, aB * NEG_SLOPE);
            float wA = __expf(aA), wB = __expf(aB);
            den += wA + wB;
#pragma unroll
            for (int q = 0; q < 4; ++q) {
                unsigned int uA = vA[q], uB = vB[q];
                acc[2 * q]     += wA * __uint_as_float(uA << 16)
                                + wB * __uint_as_float(uB << 16);
                acc[2 * q + 1] += wA * __uint_as_float(uA & 0xffff0000u)
                                + wB * __uint_as_float(uB & 0xffff0000u);
            }
        }
        for (; eb < deg; eb += 4) {
            int slot = eb + g;
            bool ok = slot < deg;
            int s = csr[e0 + (ok ? slot : 0)];
            float aval = as1[s * 8 + hh];
            unsigned int r = (unsigned int)s << 6;
            u32x4 v = *((const u32x4*)(h1w + r + wb));
            float al = aval + adst; al = fmaxf(al, al * NEG_SLOPE);
            float wt = ok ? __expf(al) : 0.f;
            den += wt;
#pragma unroll
            for (int q = 0; q < 4; ++q) {
                unsigned int u = v[q];
                acc[2 * q]     += wt * __uint_as_float(u << 16);
                acc[2 * q + 1] += wt * __uint_as_float(u & 0xffff0000u);
            }
        }
        // reduce over the 4 edge slots (lane bits 4,5) -> ALL lanes hold sums
#pragma unroll
        for (int q = 0; q < 8; ++q) {
            acc[q] += __shfl_xor(acc[q], 16, 64);
            acc[q] += __shfl_xor(acc[q], 32, 64);
        }
        den += __shfl_xor(den, 16, 64);
        den += __shfl_xor(den, 32, 64);

        // ---- fused epilogue (all 64 lanes, pure registers) ----
        float inv = 1.f / (den + 1e-16f);
        float p0 = 0.f, p1 = 0.f, p2 = 0.f, p3 = 0.f;
#pragma unroll
        for (int q = 0; q < 8; ++q) {
            float v = acc[q] * inv + b1f[q];
            v = (v > 0.f) ? v : (__expf(v) - 1.f);   // ELU
            p0 += v * w2f[q * 4 + 0];
            p1 += v * w2f[q * 4 + 1];
            p2 += v * w2f[q * 4 + 2];
            p3 += v * w2f[q * 4 + 3];
        }
#pragma unroll
        for (int msk = 8; msk >= 1; msk >>= 1) {
            p0 += __shfl_xor(p0, msk, 64);
            p1 += __shfl_xor(p1, msk, 64);
            p2 += __shfl_xor(p2, msk, 64);
            p3 += __shfl_xor(p3, msk, 64);
        }
        float sa = p0 * awsf[0] + p1 * awsf[1] + p2 * awsf[2] + p3 * awsf[3];
        float da = p0 * awdf[0] + p1 * awdf[1] + p2 * awdf[2] + p3 * awdf[3];
        sa += __shfl_xor(sa, 16, 64); sa += __shfl_xor(sa, 32, 64);
        da += __shfl_xor(da, 16, 64); da += __shfl_xor(da, 32, 64);
        if (l == 0) { as2[n] = sa; ad2[n] = da; }
        if (c8 == 0) {
            uint2 pk;
            pk.x = ((unsigned int)f2bf(p1) << 16) | f2bf(p0);
            pk.y = ((unsigned int)f2bf(p3) << 16) | f2bf(p2);
            *((uint2*)(h2b + (size_t)n * NCLS + g * 4)) = pk;
        }
    }
}

// ---------------- layer 2 aggregate (bf16 gather, unrolled x4) + log_softmax ----

__global__ __launch_bounds__(256) void k_agg2(const int* __restrict__ off,
                                              const int* __restrict__ csr,
                                              const float* __restrict__ as2,
                                              const float* __restrict__ ad2,
                                              const unsigned short* __restrict__ h2b,
                                              const float* __restrict__ b2,
                                              float* __restrict__ outp) {
    int gpos = threadIdx.x >> 4, c = threadIdx.x & 15;
    int n = blockIdx.x * 16 + gpos;
    if (n >= N) return;
    int e0 = off[n], e1 = off[n + 1];
    float adst = ad2[n];
    float den = 0.f, acc = 0.f;
    int e = e0;
    for (; e + 4 <= e1; e += 4) {
        int s0 = csr[e], s1 = csr[e + 1], s2 = csr[e + 2], s3 = csr[e + 3];
        float x0 = as2[s0], x1 = as2[s1], x2 = as2[s2], x3 = as2[s3];
        unsigned short m0 = h2b[s0 * NCLS + c], m1 = h2b[s1 * NCLS + c];
        unsigned short m2 = h2b[s2 * NCLS + c], m3 = h2b[s3 * NCLS + c];
        float a0 = x0 + adst; a0 = fmaxf(a0, a0 * NEG_SLOPE);
        float a1 = x1 + adst; a1 = fmaxf(a1, a1 * NEG_SLOPE);
        float a2 = x2 + adst; a2 = fmaxf(a2, a2 * NEG_SLOPE);
        float a3 = x3 + adst; a3 = fmaxf(a3, a3 * NEG_SLOPE);
        float w0 = __expf(a0), w1 = __expf(a1), w2 = __expf(a2), w3 = __expf(a3);
        den += (w0 + w1) + (w2 + w3);
        acc += w0 * bf2f(m0) + w1 * bf2f(m1) + w2 * bf2f(m2) + w3 * bf2f(m3);
    }
    for (; e < e1; ++e) {
        int s = csr[e];
        float al = as2[s] + adst;
        al = fmaxf(al, al * NEG_SLOPE);
        float wt = __expf(al);
        den += wt;
        acc += wt * bf2f(h2b[s * NCLS + c]);
    }
    float v = acc / (den + 1e-16f) + b2[c];
    float mx = v;
#pragma unroll
    for (int msk = 8; msk >= 1; msk >>= 1) mx = fmaxf(mx, __shfl_xor(mx, msk, 64));
    float ex = __expf(v - mx), se = ex;
#pragma unroll
    for (int msk = 8; msk >= 1; msk >>= 1) se += __shfl_xor(se, msk, 64);
    outp[n * NCLS + c] = v - mx - __logf(se);
}

// ---------------- launch ----------------

extern "C" void kernel_launch(void* const* d_in, const int* in_sizes, int n_in,
                              void* d_out, int out_size, void* d_ws, size_t ws_size,
                              hipStream_t stream) {
    const float* x        = (const float*)d_in[0];
    const int*   ei       = (const int*)d_in[1];
    const float* W1       = (const float*)d_in[2];
    const float* att_src1 = (const float*)d_in[3];
    const float* att_dst1 = (const float*)d_in[4];
    const float* b1       = (const float*)d_in[5];
    const float* W2       = (const float*)d_in[6];
    const float* att_src2 = (const float*)d_in[7];
    const float* att_dst2 = (const float*)d_in[8];
    const float* b2       = (const float*)d_in[9];
    float* outp = (float*)d_out;

    char* p = (char*)d_ws;
    unsigned short* h1m   = (unsigned short*)p; p += (size_t)N * HC * 2;   // 25.6MB
    unsigned short* h2b   = (unsigned short*)p; p += (size_t)N * NCLS * 2; // 3.2MB
    float* as1  = (float*)p; p += (size_t)N * H * 4;                       // 3.2MB
    float* ad1  = (float*)p; p += (size_t)N * H * 4;                       // 3.2MB
    float* as2  = (float*)p; p += (size_t)N * 4;
    float* ad2  = (float*)p; p += (size_t)N * 4;
    unsigned short* w1x = (unsigned short*)p; p += (size_t)144 * F * 2;    // 73.7KB
    unsigned int* pairs = (unsigned int*)p; p += (size_t)ETOT * 4;         // 6.8MB
    int* csr    = (int*)p;   p += (size_t)ETOT * 4;
    int* off    = (int*)p;   p += (size_t)(N + 1) * 4;
    int* bcnt   = (int*)p;   p += (size_t)NBUCK * 4;
    int* boff   = (int*)p;   p += (size_t)NBUCK * 4;
    int* bcur   = (int*)p;   p += (size_t)NBUCK * 4;

    hipMemsetAsync(bcnt, 0, (size_t)NBUCK * 4, stream);

    k_bhist<<<NTILE, 256, 0, stream>>>(ei, bcnt);
    k_bscan<<<1, 512, 0, stream>>>(bcnt, boff, bcur, off);
    k_part<<<NTILE, 256, 0, stream>>>(ei, bcur, pairs);
    k_bsort<<<NBUCK, 256, 0, stream>>>(pairs, bcnt, boff, csr, off);

    k_w1cast<<<(HC * F + 255) / 256, 256, 0, stream>>>(W1, w1x);
    k_wext<<<16, 256, 0, stream>>>(W1, att_src1, att_dst1, w1x);
    k_gemm1<<<(N + 63) / 64, 256, 0, stream>>>(x, w1x, h1m, as1, ad1);
    k_agg1<<<4096, 256, 0, stream>>>(off, csr, (const unsigned int*)h1m,
                                     as1, ad1, b1, W2, att_src2, att_dst2,
                                     h2b, as2, ad2);

    k_agg2<<<(N + 15) / 16, 256, 0, stream>>>(off, csr, as2, ad2, h2b, b2, outp);
}

// Round 14
// 284.733 us; speedup vs baseline: 1.4324x; 1.4324x over previous
//
#include <hip/hip_runtime.h>
#include <hip/hip_bf16.h>
#include <stdint.h>

constexpr int N     = 100000;
constexpr int E     = 1600000;
constexpr int ETOT  = E + N;
constexpr int F     = 256;
constexpr int H     = 8;
constexpr int C     = 16;
constexpr int HC    = H * C;      // 128
constexpr int NCLS  = 16;
constexpr float NEG_SLOPE = 0.2f;

constexpr int BSHIFT = 8;                       // 256 dsts per bucket
constexpr int NBUCK  = (N + 255) >> BSHIFT;     // 391
constexpr int BCAP   = 8192;
constexpr int TILE   = 16384;
constexpr int NTILE  = (ETOT + TILE - 1) / TILE;

typedef __attribute__((ext_vector_type(8))) short short8;
typedef __attribute__((ext_vector_type(4))) float f32x4;
typedef __attribute__((ext_vector_type(4))) unsigned int u32x4;

__device__ inline unsigned short f2bf(float f) {
    union { float f; unsigned int u; } v{f};
    unsigned int r = v.u + 0x7FFF + ((v.u >> 16) & 1);   // RNE
    return (unsigned short)(r >> 16);
}
__device__ inline float bf2f(unsigned short s) {
    union { unsigned int u; float f; } v{(unsigned int)s << 16};
    return v.f;
}

// ---------------- CSR build: LDS-staged two-level counting sort (proven chain) ----

__global__ __launch_bounds__(256) void k_bhist(const int* __restrict__ ei,
                                               int* __restrict__ bcnt) {
    __shared__ int h[NBUCK];
    for (int i = threadIdx.x; i < NBUCK; i += 256) h[i] = 0;
    __syncthreads();
    int t0 = blockIdx.x * TILE;
    int t1 = (t0 + TILE < ETOT) ? t0 + TILE : ETOT;
    for (int e = t0 + threadIdx.x; e < t1; e += 256) {
        int d = (e < E) ? ei[E + e] : (e - E);
        atomicAdd(&h[d >> BSHIFT], 1);
    }
    __syncthreads();
    for (int i = threadIdx.x; i < NBUCK; i += 256) {
        int c = h[i];
        if (c) atomicAdd(&bcnt[i], c);
    }
}

__global__ void k_bscan(const int* __restrict__ bcnt, int* __restrict__ boff,
                        int* __restrict__ bcur, int* __restrict__ off) {
    __shared__ int s[512];
    int tid = threadIdx.x;
    int v = (tid < NBUCK) ? bcnt[tid] : 0;
    s[tid] = v; __syncthreads();
    for (int ofs = 1; ofs < 512; ofs <<= 1) {
        int t = (tid >= ofs) ? s[tid - ofs] : 0;
        __syncthreads();
        s[tid] += t;
        __syncthreads();
    }
    if (tid < NBUCK) { int ex = s[tid] - v; boff[tid] = ex; bcur[tid] = ex; }
    if (tid == 0) off[N] = ETOT;
}

__global__ __launch_bounds__(256) void k_part(const int* __restrict__ ei,
                                              int* __restrict__ bcur,
                                              unsigned int* __restrict__ pairs) {
    __shared__ int h[NBUCK];
    __shared__ int base[NBUCK];
    int t0 = blockIdx.x * TILE;
    int t1 = (t0 + TILE < ETOT) ? t0 + TILE : ETOT;
    for (int i = threadIdx.x; i < NBUCK; i += 256) h[i] = 0;
    __syncthreads();
    for (int e = t0 + threadIdx.x; e < t1; e += 256) {
        int d = (e < E) ? ei[E + e] : (e - E);
        atomicAdd(&h[d >> BSHIFT], 1);
    }
    __syncthreads();
    for (int i = threadIdx.x; i < NBUCK; i += 256) {
        int c = h[i];
        base[i] = c ? atomicAdd(&bcur[i], c) : 0;
    }
    __syncthreads();
    for (int i = threadIdx.x; i < NBUCK; i += 256) h[i] = 0;
    __syncthreads();
    for (int e = t0 + threadIdx.x; e < t1; e += 256) {
        int s, d;
        if (e < E) { s = ei[e]; d = ei[E + e]; } else { s = e - E; d = s; }
        int b = d >> BSHIFT;
        int r = atomicAdd(&h[b], 1);
        pairs[base[b] + r] = ((unsigned)s << 8) | (unsigned)(d & 255);
    }
}

__global__ __launch_bounds__(256) void k_bsort(const unsigned int* __restrict__ pairs,
                                               const int* __restrict__ bcnt,
                                               const int* __restrict__ boff,
                                               int* __restrict__ csr,
                                               int* __restrict__ off) {
    __shared__ int srcs[BCAP];
    __shared__ int csrs[BCAP];
    __shared__ unsigned char dl[BCAP];
    __shared__ int hist[256];
    __shared__ int sc[256];
    int b = blockIdx.x;
    int nb = bcnt[b]; if (nb > BCAP) nb = BCAP;
    int base = boff[b];
    int dbase = b << BSHIFT;
    int ndst = (N - dbase < 256) ? (N - dbase) : 256;
    int tid = threadIdx.x;

    for (int i = tid; i < nb; i += 256) {
        unsigned int p = pairs[base + i];
        srcs[i] = (int)(p >> 8);
        dl[i] = (unsigned char)(p & 255);
    }
    hist[tid] = 0;
    __syncthreads();
    for (int i = tid; i < nb; i += 256) atomicAdd(&hist[dl[i]], 1);
    __syncthreads();
    int v = hist[tid];
    sc[tid] = v;
    __syncthreads();
    for (int ofs = 1; ofs < 256; ofs <<= 1) {
        int t = (tid >= ofs) ? sc[tid - ofs] : 0;
        __syncthreads();
        sc[tid] += t;
        __syncthreads();
    }
    int lo = sc[tid] - v;
    if (tid < ndst) off[dbase + tid] = base + lo;
    hist[tid] = lo;
    __syncthreads();
    for (int i = tid; i < nb; i += 256) {
        int r = atomicAdd(&hist[dl[i]], 1);
        csrs[r] = srcs[i];
    }
    __syncthreads();
    for (int i = tid; i < nb; i += 256) csr[base + i] = csrs[i];
}

// ---------------- weight prep: w1x rows 0..127 = bf16(W1); 128..143 = score cols

__global__ void k_w1cast(const float* __restrict__ W1, unsigned short* __restrict__ w1x) {
    int i = blockIdx.x * 256 + threadIdx.x;
    if (i < HC * F) w1x[i] = f2bf(W1[i]);
}

__global__ void k_wext(const float* __restrict__ W1,
                       const float* __restrict__ aws, const float* __restrict__ awd,
                       unsigned short* __restrict__ w1x) {
    int r = blockIdx.x;          // 0..15: 0-7 src-heads, 8-15 dst-heads
    int k = threadIdx.x;         // 0..255
    int h = r & 7;
    const float* aw = (r < 8) ? aws : awd;
    float acc = 0.f;
#pragma unroll
    for (int c = 0; c < 16; ++c)
        acc += aw[h * 16 + c] * W1[(size_t)(h * 16 + c) * F + k];
    w1x[(size_t)(128 + r) * F + k] = f2bf(acc);
}

// ---------------- gemm1: h1m = bf16(x)@bf16(W1)^T, fused att scores ----------
// No LDS: all B-fragments read straight from global w1x (73.7KB, L2-resident,
// shared by every block) -> higher occupancy for the 102MB x stream.

__global__ __launch_bounds__(256) void k_gemm1(const float* __restrict__ x,
                                               const unsigned short* __restrict__ w1x,
                                               unsigned short* __restrict__ h1m,
                                               float* __restrict__ as1,
                                               float* __restrict__ ad1) {
    int wid = threadIdx.x >> 6, lane = threadIdx.x & 63;
    int r16 = lane & 15, g = lane >> 4;
    int m = blockIdx.x * 64 + wid * 16 + r16;
    int mc = (m < N) ? m : (N - 1);
    const float* xr = x + (size_t)mc * F;
    const unsigned short* wrow = w1x + (size_t)r16 * F;        // B rows r16, +16,...
    const unsigned short* wext = w1x + (size_t)(128 + r16) * F;

    f32x4 acc[9];
#pragma unroll
    for (int nf = 0; nf < 9; ++nf) acc[nf] = (f32x4){0.f, 0.f, 0.f, 0.f};

#pragma unroll
    for (int kk = 0; kk < 8; ++kk) {
        f32x4 a0 = *((const f32x4*)(xr + kk * 32 + g * 8));
        f32x4 a1 = *((const f32x4*)(xr + kk * 32 + g * 8 + 4));
        short8 af;
#pragma unroll
        for (int j = 0; j < 4; ++j) {
            af[j]     = (short)f2bf(a0[j]);
            af[4 + j] = (short)f2bf(a1[j]);
        }
#pragma unroll
        for (int nf = 0; nf < 8; ++nf) {
            short8 bf = *((const short8*)(wrow + (size_t)(nf * 16) * F + kk * 32 + g * 8));
            acc[nf] = __builtin_amdgcn_mfma_f32_16x16x32_bf16(af, bf, acc[nf], 0, 0, 0);
        }
        short8 bfx = *((const short8*)(wext + kk * 32 + g * 8));
        acc[8] = __builtin_amdgcn_mfma_f32_16x16x32_bf16(af, bfx, acc[8], 0, 0, 0);
    }

    int orow = blockIdx.x * 64 + wid * 16 + g * 4;
#pragma unroll
    for (int j = 0; j < 4; ++j) {
        int rr = orow + j;
        if (rr >= N) continue;
        unsigned short* dst = h1m + (size_t)rr * HC + r16;
#pragma unroll
        for (int nf = 0; nf < 8; ++nf) dst[nf * 16] = f2bf(acc[nf][j]);
        float v = acc[8][j];
        if (r16 < 8) as1[rr * 8 + r16] = v;
        else         ad1[rr * 8 + (r16 - 8)] = v;
    }
}

// ---- layer 1 aggregate + FUSED layer-2 GEMM + att scores (round-10 proven) ----
// 4 slots (g=l>>4) x 16 lanes (c8=l&15, 8 channels); x2 unrolled slot loop.
// Epilogue runs on ALL 64 lanes; W2 in LDS with [q*16+c8]*17+j layout.

__global__ __launch_bounds__(256) void k_agg1(const int* __restrict__ off,
                                              const int* __restrict__ csr,
                                              const unsigned int* __restrict__ h1w,
                                              const float* __restrict__ as1,
                                              const float* __restrict__ ad1,
                                              const float* __restrict__ b1,
                                              const float* __restrict__ W2,
                                              const float* __restrict__ aw_s2,
                                              const float* __restrict__ aw_d2,
                                              unsigned short* __restrict__ h2b,
                                              float* __restrict__ as2,
                                              float* __restrict__ ad2) {
    __shared__ float W2s[128 * 17];   // [ (q*16+c8)*17 + j ], 8.5KB
    for (int i = threadIdx.x; i < HC * NCLS; i += 256) {
        int j = i >> 7, k = i & 127;               // i = j*128 + k
        int c8 = k >> 3, q = k & 7;
        W2s[(q * 16 + c8) * 17 + j] = W2[i];
    }
    __syncthreads();

    int w = threadIdx.x >> 6, l = threadIdx.x & 63;
    int n = blockIdx.x * 4 + w;
    if (n >= N) return;
    int g  = l >> 4;            // edge slot 0..3
    int c8 = l & 15;            // channel block (8 bf16)
    int hh = c8 >> 1;           // head of this block
    unsigned int wb = (unsigned int)(c8 * 4);
    int e0 = off[n], e1 = off[n + 1];
    int deg = e1 - e0;
    float adst = ad1[n * 8 + hh];
    float den = 0.f;
    float acc[8] = {0.f, 0.f, 0.f, 0.f, 0.f, 0.f, 0.f, 0.f};

    int eb = 0;
    for (; eb + 8 <= deg; eb += 8) {
        int sA = csr[e0 + eb + g];
        int sB = csr[e0 + eb + 4 + g];
        float avA = as1[sA * 8 + hh];
        float avB = as1[sB * 8 + hh];
        unsigned int rA = (unsigned int)sA << 6;
        unsigned int rB = (unsigned int)sB << 6;
        u32x4 vA = *((const u32x4*)(h1w + rA + wb));
        u32x4 vB = *((const u32x4*)(h1w + rB + wb));
        float aA = avA + adst; aA = fmaxf(aA, aA * NEG_SLOPE);
        float aB = avB + adst; aB = fmaxf(aB, aB * NEG_SLOPE);
        float wA = __expf(aA), wB = __expf(aB);
        den += wA + wB;
#pragma unroll
        for (int q = 0; q < 4; ++q) {
            unsigned int uA = vA[q], uB = vB[q];
            acc[2 * q]     += wA * __uint_as_float(uA << 16)
                            + wB * __uint_as_float(uB << 16);
            acc[2 * q + 1] += wA * __uint_as_float(uA & 0xffff0000u)
                            + wB * __uint_as_float(uB & 0xffff0000u);
        }
    }
    for (; eb < deg; eb += 4) {
        int slot = eb + g;
        bool ok = slot < deg;
        int s = csr[e0 + (ok ? slot : 0)];
        float aval = as1[s * 8 + hh];
        unsigned int r = (unsigned int)s << 6;
        u32x4 v = *((const u32x4*)(h1w + r + wb));
        float al = aval + adst; al = fmaxf(al, al * NEG_SLOPE);
        float wt = ok ? __expf(al) : 0.f;
        den += wt;
#pragma unroll
        for (int q = 0; q < 4; ++q) {
            unsigned int u = v[q];
            acc[2 * q]     += wt * __uint_as_float(u << 16);
            acc[2 * q + 1] += wt * __uint_as_float(u & 0xffff0000u);
        }
    }
    // reduce over the 4 edge slots (lane bits 4,5) -> ALL lanes hold the sums
#pragma unroll
    for (int q = 0; q < 8; ++q) {
        acc[q] += __shfl_xor(acc[q], 16, 64);
        acc[q] += __shfl_xor(acc[q], 32, 64);
    }
    den += __shfl_xor(den, 16, 64);
    den += __shfl_xor(den, 32, 64);

    // ---- fused epilogue (all 64 lanes) ----
    float inv = 1.f / (den + 1e-16f);
    float v8[8];
#pragma unroll
    for (int q = 0; q < 8; ++q) {
        float v = acc[q] * inv + b1[c8 * 8 + q];
        v8[q] = (v > 0.f) ? v : (__expf(v) - 1.f);   // ELU: out1 channel c8*8+q
    }
    // gemm2 partials: lane covers channels c8*8+q, classes g*4..g*4+3
    float p0 = 0.f, p1 = 0.f, p2 = 0.f, p3 = 0.f;
#pragma unroll
    for (int q = 0; q < 8; ++q) {
        const float* wr = &W2s[(q * 16 + c8) * 17 + g * 4];
        p0 += v8[q] * wr[0];
        p1 += v8[q] * wr[1];
        p2 += v8[q] * wr[2];
        p3 += v8[q] * wr[3];
    }
    // butterfly over c8 (bits 0..3): all lanes in slot g hold h2[g*4+0..3]
#pragma unroll
    for (int msk = 8; msk >= 1; msk >>= 1) {
        p0 += __shfl_xor(p0, msk, 64);
        p1 += __shfl_xor(p1, msk, 64);
        p2 += __shfl_xor(p2, msk, 64);
        p3 += __shfl_xor(p3, msk, 64);
    }
    // att scores for layer 2
    float sa = p0 * aw_s2[g * 4] + p1 * aw_s2[g * 4 + 1]
             + p2 * aw_s2[g * 4 + 2] + p3 * aw_s2[g * 4 + 3];
    float da = p0 * aw_d2[g * 4] + p1 * aw_d2[g * 4 + 1]
             + p2 * aw_d2[g * 4 + 2] + p3 * aw_d2[g * 4 + 3];
    sa += __shfl_xor(sa, 16, 64); sa += __shfl_xor(sa, 32, 64);
    da += __shfl_xor(da, 16, 64); da += __shfl_xor(da, 32, 64);
    if (l == 0) { as2[n] = sa; ad2[n] = da; }
    if (c8 < 4) {
        float h2v = p0;
        h2v = (c8 == 1) ? p1 : h2v;
        h2v = (c8 == 2) ? p2 : h2v;
        h2v = (c8 == 3) ? p3 : h2v;
        h2b[(size_t)n * NCLS + g * 4 + c8] = f2bf(h2v);
    }
}

// ---------------- layer 2 aggregate (bf16 gather, unrolled x4) + log_softmax ----

__global__ __launch_bounds__(256) void k_agg2(const int* __restrict__ off,
                                              const int* __restrict__ csr,
                                              const float* __restrict__ as2,
                                              const float* __restrict__ ad2,
                                              const unsigned short* __restrict__ h2b,
                                              const float* __restrict__ b2,
                                              float* __restrict__ outp) {
    int gpos = threadIdx.x >> 4, c = threadIdx.x & 15;
    int n = blockIdx.x * 16 + gpos;
    if (n >= N) return;
    int e0 = off[n], e1 = off[n + 1];
    float adst = ad2[n];
    float den = 0.f, acc = 0.f;
    int e = e0;
    for (; e + 4 <= e1; e += 4) {
        int s0 = csr[e], s1 = csr[e + 1], s2 = csr[e + 2], s3 = csr[e + 3];
        float x0 = as2[s0], x1 = as2[s1], x2 = as2[s2], x3 = as2[s3];
        unsigned short m0 = h2b[s0 * NCLS + c], m1 = h2b[s1 * NCLS + c];
        unsigned short m2 = h2b[s2 * NCLS + c], m3 = h2b[s3 * NCLS + c];
        float a0 = x0 + adst; a0 = fmaxf(a0, a0 * NEG_SLOPE);
        float a1 = x1 + adst; a1 = fmaxf(a1, a1 * NEG_SLOPE);
        float a2 = x2 + adst; a2 = fmaxf(a2, a2 * NEG_SLOPE);
        float a3 = x3 + adst; a3 = fmaxf(a3, a3 * NEG_SLOPE);
        float w0 = __expf(a0), w1 = __expf(a1), w2 = __expf(a2), w3 = __expf(a3);
        den += (w0 + w1) + (w2 + w3);
        acc += w0 * bf2f(m0) + w1 * bf2f(m1) + w2 * bf2f(m2) + w3 * bf2f(m3);
    }
    for (; e < e1; ++e) {
        int s = csr[e];
        float al = as2[s] + adst;
        al = fmaxf(al, al * NEG_SLOPE);
        float wt = __expf(al);
        den += wt;
        acc += wt * bf2f(h2b[s * NCLS + c]);
    }
    float v = acc / (den + 1e-16f) + b2[c];
    float mx = v;
#pragma unroll
    for (int msk = 8; msk >= 1; msk >>= 1) mx = fmaxf(mx, __shfl_xor(mx, msk, 64));
    float ex = __expf(v - mx), se = ex;
#pragma unroll
    for (int msk = 8; msk >= 1; msk >>= 1) se += __shfl_xor(se, msk, 64);
    outp[n * NCLS + c] = v - mx - __logf(se);
}

// ---------------- launch ----------------

extern "C" void kernel_launch(void* const* d_in, const int* in_sizes, int n_in,
                              void* d_out, int out_size, void* d_ws, size_t ws_size,
                              hipStream_t stream) {
    const float* x        = (const float*)d_in[0];
    const int*   ei       = (const int*)d_in[1];
    const float* W1       = (const float*)d_in[2];
    const float* att_src1 = (const float*)d_in[3];
    const float* att_dst1 = (const float*)d_in[4];
    const float* b1       = (const float*)d_in[5];
    const float* W2       = (const float*)d_in[6];
    const float* att_src2 = (const float*)d_in[7];
    const float* att_dst2 = (const float*)d_in[8];
    const float* b2       = (const float*)d_in[9];
    float* outp = (float*)d_out;

    char* p = (char*)d_ws;
    unsigned short* h1m   = (unsigned short*)p; p += (size_t)N * HC * 2;   // 25.6MB
    unsigned short* h2b   = (unsigned short*)p; p += (size_t)N * NCLS * 2; // 3.2MB
    float* as1  = (float*)p; p += (size_t)N * H * 4;                       // 3.2MB
    float* ad1  = (float*)p; p += (size_t)N * H * 4;                       // 3.2MB
    float* as2  = (float*)p; p += (size_t)N * 4;
    float* ad2  = (float*)p; p += (size_t)N * 4;
    unsigned short* w1x = (unsigned short*)p; p += (size_t)144 * F * 2;    // 73.7KB
    unsigned int* pairs = (unsigned int*)p; p += (size_t)ETOT * 4;         // 6.8MB
    int* csr    = (int*)p;   p += (size_t)ETOT * 4;
    int* off    = (int*)p;   p += (size_t)(N + 1) * 4;
    int* bcnt   = (int*)p;   p += (size_t)NBUCK * 4;
    int* boff   = (int*)p;   p += (size_t)NBUCK * 4;
    int* bcur   = (int*)p;   p += (size_t)NBUCK * 4;

    hipMemsetAsync(bcnt, 0, (size_t)NBUCK * 4, stream);

    k_bhist<<<NTILE, 256, 0, stream>>>(ei, bcnt);
    k_bscan<<<1, 512, 0, stream>>>(bcnt, boff, bcur, off);
    k_part<<<NTILE, 256, 0, stream>>>(ei, bcur, pairs);
    k_bsort<<<NBUCK, 256, 0, stream>>>(pairs, bcnt, boff, csr, off);

    k_w1cast<<<(HC * F + 255) / 256, 256, 0, stream>>>(W1, w1x);
    k_wext<<<16, 256, 0, stream>>>(W1, att_src1, att_dst1, w1x);
    k_gemm1<<<(N + 63) / 64, 256, 0, stream>>>(x, w1x, h1m, as1, ad1);
    k_agg1<<<(N + 3) / 4, 256, 0, stream>>>(off, csr, (const unsigned int*)h1m,
                                            as1, ad1, b1, W2, att_src2, att_dst2,
                                            h2b, as2, ad2);

    k_agg2<<<(N + 15) / 16, 256, 0, stream>>>(off, csr, as2, ad2, h2b, b2, outp);
}

// Round 15
// 267.076 us; speedup vs baseline: 1.5272x; 1.0661x over previous
//
#include <hip/hip_runtime.h>
#include <hip/hip_bf16.h>
#include <stdint.h>

constexpr int N     = 100000;
constexpr int E     = 1600000;
constexpr int ETOT  = E + N;
constexpr int F     = 256;
constexpr int H     = 8;
constexpr int C     = 16;
constexpr int HC    = H * C;      // 128
constexpr int NCLS  = 16;
constexpr float NEG_SLOPE = 0.2f;

constexpr int BSHIFT = 8;                       // 256 dsts per bucket
constexpr int NBUCK  = (N + 255) >> BSHIFT;     // 391
constexpr int BCAP   = 8192;
constexpr int TILE   = 16384;
constexpr int NTILE  = (ETOT + TILE - 1) / TILE;

typedef __attribute__((ext_vector_type(8))) short short8;
typedef __attribute__((ext_vector_type(4))) float f32x4;
typedef __attribute__((ext_vector_type(4))) unsigned int u32x4;

__device__ inline unsigned short f2bf(float f) {
    union { float f; unsigned int u; } v{f};
    unsigned int r = v.u + 0x7FFF + ((v.u >> 16) & 1);   // RNE
    return (unsigned short)(r >> 16);
}
__device__ inline float bf2f(unsigned short s) {
    union { unsigned int u; float f; } v{(unsigned int)s << 16};
    return v.f;
}

// ---------------- CSR build: LDS-staged two-level counting sort (proven chain) ----

__global__ __launch_bounds__(256) void k_bhist(const int* __restrict__ ei,
                                               int* __restrict__ bcnt) {
    __shared__ int h[NBUCK];
    for (int i = threadIdx.x; i < NBUCK; i += 256) h[i] = 0;
    __syncthreads();
    int t0 = blockIdx.x * TILE;
    int t1 = (t0 + TILE < ETOT) ? t0 + TILE : ETOT;
    for (int e = t0 + threadIdx.x; e < t1; e += 256) {
        int d = (e < E) ? ei[E + e] : (e - E);
        atomicAdd(&h[d >> BSHIFT], 1);
    }
    __syncthreads();
    for (int i = threadIdx.x; i < NBUCK; i += 256) {
        int c = h[i];
        if (c) atomicAdd(&bcnt[i], c);
    }
}

__global__ void k_bscan(const int* __restrict__ bcnt, int* __restrict__ boff,
                        int* __restrict__ bcur, int* __restrict__ off) {
    __shared__ int s[512];
    int tid = threadIdx.x;
    int v = (tid < NBUCK) ? bcnt[tid] : 0;
    s[tid] = v; __syncthreads();
    for (int ofs = 1; ofs < 512; ofs <<= 1) {
        int t = (tid >= ofs) ? s[tid - ofs] : 0;
        __syncthreads();
        s[tid] += t;
        __syncthreads();
    }
    if (tid < NBUCK) { int ex = s[tid] - v; boff[tid] = ex; bcur[tid] = ex; }
    if (tid == 0) off[N] = ETOT;
}

__global__ __launch_bounds__(256) void k_part(const int* __restrict__ ei,
                                              int* __restrict__ bcur,
                                              unsigned int* __restrict__ pairs) {
    __shared__ int h[NBUCK];
    __shared__ int base[NBUCK];
    int t0 = blockIdx.x * TILE;
    int t1 = (t0 + TILE < ETOT) ? t0 + TILE : ETOT;
    for (int i = threadIdx.x; i < NBUCK; i += 256) h[i] = 0;
    __syncthreads();
    for (int e = t0 + threadIdx.x; e < t1; e += 256) {
        int d = (e < E) ? ei[E + e] : (e - E);
        atomicAdd(&h[d >> BSHIFT], 1);
    }
    __syncthreads();
    for (int i = threadIdx.x; i < NBUCK; i += 256) {
        int c = h[i];
        base[i] = c ? atomicAdd(&bcur[i], c) : 0;
    }
    __syncthreads();
    for (int i = threadIdx.x; i < NBUCK; i += 256) h[i] = 0;
    __syncthreads();
    for (int e = t0 + threadIdx.x; e < t1; e += 256) {
        int s, d;
        if (e < E) { s = ei[e]; d = ei[E + e]; } else { s = e - E; d = s; }
        int b = d >> BSHIFT;
        int r = atomicAdd(&h[b], 1);
        pairs[base[b] + r] = ((unsigned)s << 8) | (unsigned)(d & 255);
    }
}

__global__ __launch_bounds__(256) void k_bsort(const unsigned int* __restrict__ pairs,
                                               const int* __restrict__ bcnt,
                                               const int* __restrict__ boff,
                                               int* __restrict__ csr,
                                               int* __restrict__ off) {
    __shared__ int srcs[BCAP];
    __shared__ int csrs[BCAP];
    __shared__ unsigned char dl[BCAP];
    __shared__ int hist[256];
    __shared__ int sc[256];
    int b = blockIdx.x;
    int nb = bcnt[b]; if (nb > BCAP) nb = BCAP;
    int base = boff[b];
    int dbase = b << BSHIFT;
    int ndst = (N - dbase < 256) ? (N - dbase) : 256;
    int tid = threadIdx.x;

    for (int i = tid; i < nb; i += 256) {
        unsigned int p = pairs[base + i];
        srcs[i] = (int)(p >> 8);
        dl[i] = (unsigned char)(p & 255);
    }
    hist[tid] = 0;
    __syncthreads();
    for (int i = tid; i < nb; i += 256) atomicAdd(&hist[dl[i]], 1);
    __syncthreads();
    int v = hist[tid];
    sc[tid] = v;
    __syncthreads();
    for (int ofs = 1; ofs < 256; ofs <<= 1) {
        int t = (tid >= ofs) ? sc[tid - ofs] : 0;
        __syncthreads();
        sc[tid] += t;
        __syncthreads();
    }
    int lo = sc[tid] - v;
    if (tid < ndst) off[dbase + tid] = base + lo;
    hist[tid] = lo;
    __syncthreads();
    for (int i = tid; i < nb; i += 256) {
        int r = atomicAdd(&hist[dl[i]], 1);
        csrs[r] = srcs[i];
    }
    __syncthreads();
    for (int i = tid; i < nb; i += 256) csr[base + i] = csrs[i];
}

// ---------------- weight prep: w1x rows 0..127 = bf16(W1); 128..143 = score cols

__global__ void k_w1cast(const float* __restrict__ W1, unsigned short* __restrict__ w1x) {
    int i = blockIdx.x * 256 + threadIdx.x;
    if (i < HC * F) w1x[i] = f2bf(W1[i]);
}

__global__ void k_wext(const float* __restrict__ W1,
                       const float* __restrict__ aws, const float* __restrict__ awd,
                       unsigned short* __restrict__ w1x) {
    int r = blockIdx.x;          // 0..15: 0-7 src-heads, 8-15 dst-heads
    int k = threadIdx.x;         // 0..255
    int h = r & 7;
    const float* aw = (r < 8) ? aws : awd;
    float acc = 0.f;
#pragma unroll
    for (int c = 0; c < 16; ++c)
        acc += aw[h * 16 + c] * W1[(size_t)(h * 16 + c) * F + k];
    w1x[(size_t)(128 + r) * F + k] = f2bf(acc);
}

// ---------------- gemm1: h1m = bf16(x)@bf16(W1)^T, fused att scores (cols 128-143)

__global__ __launch_bounds__(256) void k_gemm1(const float* __restrict__ x,
                                               const unsigned short* __restrict__ w1x,
                                               unsigned short* __restrict__ h1m,
                                               float* __restrict__ as1,
                                               float* __restrict__ ad1) {
    __shared__ unsigned short Ws[HC * F];  // 64KB, XOR-swizzled 16B chunks (rows 0..127)
    for (int i = threadIdx.x; i < 4096; i += 256) {
        int row = i >> 5;
        int c16 = i & 31;
        u32x4 v = ((const u32x4*)w1x)[i];
        int byte = row * 512 + ((c16 * 16) ^ ((row & 7) << 4));
        *((u32x4*)((char*)Ws + byte)) = v;
    }
    __syncthreads();

    int wid = threadIdx.x >> 6, lane = threadIdx.x & 63;
    int r16 = lane & 15, g = lane >> 4;
    int m = blockIdx.x * 64 + wid * 16 + r16;
    int mc = (m < N) ? m : (N - 1);
    const float* xr = x + (size_t)mc * F;
    const unsigned short* wext = w1x + (size_t)(128 + r16) * F;

    f32x4 acc[9];
#pragma unroll
    for (int nf = 0; nf < 9; ++nf) acc[nf] = (f32x4){0.f, 0.f, 0.f, 0.f};

#pragma unroll
    for (int kk = 0; kk < 8; ++kk) {
        f32x4 a0 = *((const f32x4*)(xr + kk * 32 + g * 8));
        f32x4 a1 = *((const f32x4*)(xr + kk * 32 + g * 8 + 4));
        short8 af;
#pragma unroll
        for (int j = 0; j < 4; ++j) {
            af[j]     = (short)f2bf(a0[j]);
            af[4 + j] = (short)f2bf(a1[j]);
        }
        int kbyte = kk * 64 + g * 16;
#pragma unroll
        for (int nf = 0; nf < 8; ++nf) {
            int row = nf * 16 + r16;
            int byte = row * 512 + (kbyte ^ ((row & 7) << 4));
            short8 bf = *((const short8*)((const char*)Ws + byte));
            acc[nf] = __builtin_amdgcn_mfma_f32_16x16x32_bf16(af, bf, acc[nf], 0, 0, 0);
        }
        short8 bfx = *((const short8*)(wext + kk * 32 + g * 8));
        acc[8] = __builtin_amdgcn_mfma_f32_16x16x32_bf16(af, bfx, acc[8], 0, 0, 0);
    }

    int orow = blockIdx.x * 64 + wid * 16 + g * 4;
#pragma unroll
    for (int j = 0; j < 4; ++j) {
        int rr = orow + j;
        if (rr >= N) continue;
        unsigned short* dst = h1m + (size_t)rr * HC + r16;
#pragma unroll
        for (int nf = 0; nf < 8; ++nf) dst[nf * 16] = f2bf(acc[nf][j]);
        float v = acc[8][j];
        if (r16 < 8) as1[rr * 8 + r16] = v;
        else         ad1[rr * 8 + (r16 - 8)] = v;
    }
}

// ---- layer 1 aggregate + FUSED layer-2 GEMM + att scores (R10 + 16-deep unroll) ----
// 4 slots (g=l>>4) x 16 lanes (c8=l&15, 8 channels); 16-edge main loop (4 records
// in flight per lane), 8/4-edge tails. Epilogue on ALL 64 lanes; W2s [q*16+c8]*17+j.

__global__ __launch_bounds__(256) void k_agg1(const int* __restrict__ off,
                                              const int* __restrict__ csr,
                                              const unsigned int* __restrict__ h1w,
                                              const float* __restrict__ as1,
                                              const float* __restrict__ ad1,
                                              const float* __restrict__ b1,
                                              const float* __restrict__ W2,
                                              const float* __restrict__ aw_s2,
                                              const float* __restrict__ aw_d2,
                                              unsigned short* __restrict__ h2b,
                                              float* __restrict__ as2,
                                              float* __restrict__ ad2) {
    __shared__ float W2s[128 * 17];   // [ (q*16+c8)*17 + j ], 8.5KB
    for (int i = threadIdx.x; i < HC * NCLS; i += 256) {
        int j = i >> 7, k = i & 127;               // i = j*128 + k
        int c8 = k >> 3, q = k & 7;
        W2s[(q * 16 + c8) * 17 + j] = W2[i];
    }
    __syncthreads();

    int w = threadIdx.x >> 6, l = threadIdx.x & 63;
    int n = blockIdx.x * 4 + w;
    if (n >= N) return;
    int g  = l >> 4;            // edge slot 0..3
    int c8 = l & 15;            // channel block (8 bf16)
    int hh = c8 >> 1;           // head of this block
    unsigned int wb = (unsigned int)(c8 * 4);
    int e0 = off[n], e1 = off[n + 1];
    int deg = e1 - e0;
    float adst = ad1[n * 8 + hh];
    float den = 0.f;
    float acc[8] = {0.f, 0.f, 0.f, 0.f, 0.f, 0.f, 0.f, 0.f};

    int eb = 0;
    for (; eb + 16 <= deg; eb += 16) {
        int sA = csr[e0 + eb + g];
        int sB = csr[e0 + eb + 4 + g];
        int sC = csr[e0 + eb + 8 + g];
        int sD = csr[e0 + eb + 12 + g];
        float avA = as1[sA * 8 + hh];
        float avB = as1[sB * 8 + hh];
        float avC = as1[sC * 8 + hh];
        float avD = as1[sD * 8 + hh];
        unsigned int rA = (unsigned int)sA << 6;
        unsigned int rB = (unsigned int)sB << 6;
        unsigned int rC = (unsigned int)sC << 6;
        unsigned int rD = (unsigned int)sD << 6;
        u32x4 vA = *((const u32x4*)(h1w + rA + wb));
        u32x4 vB = *((const u32x4*)(h1w + rB + wb));
        u32x4 vC = *((const u32x4*)(h1w + rC + wb));
        u32x4 vD = *((const u32x4*)(h1w + rD + wb));
        float aA = avA + adst; aA = fmaxf(aA, aA * NEG_SLOPE);
        float aB = avB + adst; aB = fmaxf(aB, aB * NEG_SLOPE);
        float aC = avC + adst; aC = fmaxf(aC, aC * NEG_SLOPE);
        float aD = avD + adst; aD = fmaxf(aD, aD * NEG_SLOPE);
        float wA = __expf(aA), wB = __expf(aB);
        float wC = __expf(aC), wD = __expf(aD);
        den += (wA + wB) + (wC + wD);
#pragma unroll
        for (int q = 0; q < 4; ++q) {
            unsigned int uA = vA[q], uB = vB[q], uC = vC[q], uD = vD[q];
            acc[2 * q]     += wA * __uint_as_float(uA << 16)
                            + wB * __uint_as_float(uB << 16)
                            + wC * __uint_as_float(uC << 16)
                            + wD * __uint_as_float(uD << 16);
            acc[2 * q + 1] += wA * __uint_as_float(uA & 0xffff0000u)
                            + wB * __uint_as_float(uB & 0xffff0000u)
                            + wC * __uint_as_float(uC & 0xffff0000u)
                            + wD * __uint_as_float(uD & 0xffff0000u);
        }
    }
    for (; eb + 8 <= deg; eb += 8) {
        int sA = csr[e0 + eb + g];
        int sB = csr[e0 + eb + 4 + g];
        float avA = as1[sA * 8 + hh];
        float avB = as1[sB * 8 + hh];
        unsigned int rA = (unsigned int)sA << 6;
        unsigned int rB = (unsigned int)sB << 6;
        u32x4 vA = *((const u32x4*)(h1w + rA + wb));
        u32x4 vB = *((const u32x4*)(h1w + rB + wb));
        float aA = avA + adst; aA = fmaxf(aA, aA * NEG_SLOPE);
        float aB = avB + adst; aB = fmaxf(aB, aB * NEG_SLOPE);
        float wA = __expf(aA), wB = __expf(aB);
        den += wA + wB;
#pragma unroll
        for (int q = 0; q < 4; ++q) {
            unsigned int uA = vA[q], uB = vB[q];
            acc[2 * q]     += wA * __uint_as_float(uA << 16)
                            + wB * __uint_as_float(uB << 16);
            acc[2 * q + 1] += wA * __uint_as_float(uA & 0xffff0000u)
                            + wB * __uint_as_float(uB & 0xffff0000u);
        }
    }
    for (; eb < deg; eb += 4) {
        int slot = eb + g;
        bool ok = slot < deg;
        int s = csr[e0 + (ok ? slot : 0)];
        float aval = as1[s * 8 + hh];
        unsigned int r = (unsigned int)s << 6;
        u32x4 v = *((const u32x4*)(h1w + r + wb));
        float al = aval + adst; al = fmaxf(al, al * NEG_SLOPE);
        float wt = ok ? __expf(al) : 0.f;
        den += wt;
#pragma unroll
        for (int q = 0; q < 4; ++q) {
            unsigned int u = v[q];
            acc[2 * q]     += wt * __uint_as_float(u << 16);
            acc[2 * q + 1] += wt * __uint_as_float(u & 0xffff0000u);
        }
    }
    // reduce over the 4 edge slots (lane bits 4,5) -> ALL lanes hold the sums
#pragma unroll
    for (int q = 0; q < 8; ++q) {
        acc[q] += __shfl_xor(acc[q], 16, 64);
        acc[q] += __shfl_xor(acc[q], 32, 64);
    }
    den += __shfl_xor(den, 16, 64);
    den += __shfl_xor(den, 32, 64);

    // ---- fused epilogue (all 64 lanes) ----
    float inv = 1.f / (den + 1e-16f);
    float v8[8];
#pragma unroll
    for (int q = 0; q < 8; ++q) {
        float v = acc[q] * inv + b1[c8 * 8 + q];
        v8[q] = (v > 0.f) ? v : (__expf(v) - 1.f);   // ELU: out1 channel c8*8+q
    }
    // gemm2 partials: lane covers channels c8*8+q, classes g*4..g*4+3
    float p0 = 0.f, p1 = 0.f, p2 = 0.f, p3 = 0.f;
#pragma unroll
    for (int q = 0; q < 8; ++q) {
        const float* wr = &W2s[(q * 16 + c8) * 17 + g * 4];
        p0 += v8[q] * wr[0];
        p1 += v8[q] * wr[1];
        p2 += v8[q] * wr[2];
        p3 += v8[q] * wr[3];
    }
    // butterfly over c8 (bits 0..3): all lanes in slot g hold h2[g*4+0..3]
#pragma unroll
    for (int msk = 8; msk >= 1; msk >>= 1) {
        p0 += __shfl_xor(p0, msk, 64);
        p1 += __shfl_xor(p1, msk, 64);
        p2 += __shfl_xor(p2, msk, 64);
        p3 += __shfl_xor(p3, msk, 64);
    }
    // att scores for layer 2
    float sa = p0 * aw_s2[g * 4] + p1 * aw_s2[g * 4 + 1]
             + p2 * aw_s2[g * 4 + 2] + p3 * aw_s2[g * 4 + 3];
    float da = p0 * aw_d2[g * 4] + p1 * aw_d2[g * 4 + 1]
             + p2 * aw_d2[g * 4 + 2] + p3 * aw_d2[g * 4 + 3];
    sa += __shfl_xor(sa, 16, 64); sa += __shfl_xor(sa, 32, 64);
    da += __shfl_xor(da, 16, 64); da += __shfl_xor(da, 32, 64);
    if (l == 0) { as2[n] = sa; ad2[n] = da; }
    if (c8 < 4) {
        float h2v = p0;
        h2v = (c8 == 1) ? p1 : h2v;
        h2v = (c8 == 2) ? p2 : h2v;
        h2v = (c8 == 3) ? p3 : h2v;
        h2b[(size_t)n * NCLS + g * 4 + c8] = f2bf(h2v);
    }
}

// ---------------- layer 2 aggregate (bf16 gather, unrolled x4) + log_softmax ----

__global__ __launch_bounds__(256) void k_agg2(const int* __restrict__ off,
                                              const int* __restrict__ csr,
                                              const float* __restrict__ as2,
                                              const float* __restrict__ ad2,
                                              const unsigned short* __restrict__ h2b,
                                              const float* __restrict__ b2,
                                              float* __restrict__ outp) {
    int gpos = threadIdx.x >> 4, c = threadIdx.x & 15;
    int n = blockIdx.x * 16 + gpos;
    if (n >= N) return;
    int e0 = off[n], e1 = off[n + 1];
    float adst = ad2[n];
    float den = 0.f, acc = 0.f;
    int e = e0;
    for (; e + 4 <= e1; e += 4) {
        int s0 = csr[e], s1 = csr[e + 1], s2 = csr[e + 2], s3 = csr[e + 3];
        float x0 = as2[s0], x1 = as2[s1], x2 = as2[s2], x3 = as2[s3];
        unsigned short m0 = h2b[s0 * NCLS + c], m1 = h2b[s1 * NCLS + c];
        unsigned short m2 = h2b[s2 * NCLS + c], m3 = h2b[s3 * NCLS + c];
        float a0 = x0 + adst; a0 = fmaxf(a0, a0 * NEG_SLOPE);
        float a1 = x1 + adst; a1 = fmaxf(a1, a1 * NEG_SLOPE);
        float a2 = x2 + adst; a2 = fmaxf(a2, a2 * NEG_SLOPE);
        float a3 = x3 + adst; a3 = fmaxf(a3, a3 * NEG_SLOPE);
        float w0 = __expf(a0), w1 = __expf(a1), w2 = __expf(a2), w3 = __expf(a3);
        den += (w0 + w1) + (w2 + w3);
        acc += w0 * bf2f(m0) + w1 * bf2f(m1) + w2 * bf2f(m2) + w3 * bf2f(m3);
    }
    for (; e < e1; ++e) {
        int s = csr[e];
        float al = as2[s] + adst;
        al = fmaxf(al, al * NEG_SLOPE);
        float wt = __expf(al);
        den += wt;
        acc += wt * bf2f(h2b[s * NCLS + c]);
    }
    float v = acc / (den + 1e-16f) + b2[c];
    float mx = v;
#pragma unroll
    for (int msk = 8; msk >= 1; msk >>= 1) mx = fmaxf(mx, __shfl_xor(mx, msk, 64));
    float ex = __expf(v - mx), se = ex;
#pragma unroll
    for (int msk = 8; msk >= 1; msk >>= 1) se += __shfl_xor(se, msk, 64);
    outp[n * NCLS + c] = v - mx - __logf(se);
}

// ---------------- launch ----------------

extern "C" void kernel_launch(void* const* d_in, const int* in_sizes, int n_in,
                              void* d_out, int out_size, void* d_ws, size_t ws_size,
                              hipStream_t stream) {
    const float* x        = (const float*)d_in[0];
    const int*   ei       = (const int*)d_in[1];
    const float* W1       = (const float*)d_in[2];
    const float* att_src1 = (const float*)d_in[3];
    const float* att_dst1 = (const float*)d_in[4];
    const float* b1       = (const float*)d_in[5];
    const float* W2       = (const float*)d_in[6];
    const float* att_src2 = (const float*)d_in[7];
    const float* att_dst2 = (const float*)d_in[8];
    const float* b2       = (const float*)d_in[9];
    float* outp = (float*)d_out;

    char* p = (char*)d_ws;
    unsigned short* h1m   = (unsigned short*)p; p += (size_t)N * HC * 2;   // 25.6MB
    unsigned short* h2b   = (unsigned short*)p; p += (size_t)N * NCLS * 2; // 3.2MB
    float* as1  = (float*)p; p += (size_t)N * H * 4;                       // 3.2MB
    float* ad1  = (float*)p; p += (size_t)N * H * 4;                       // 3.2MB
    float* as2  = (float*)p; p += (size_t)N * 4;
    float* ad2  = (float*)p; p += (size_t)N * 4;
    unsigned short* w1x = (unsigned short*)p; p += (size_t)144 * F * 2;    // 73.7KB
    unsigned int* pairs = (unsigned int*)p; p += (size_t)ETOT * 4;         // 6.8MB
    int* csr    = (int*)p;   p += (size_t)ETOT * 4;
    int* off    = (int*)p;   p += (size_t)(N + 1) * 4;
    int* bcnt   = (int*)p;   p += (size_t)NBUCK * 4;
    int* boff   = (int*)p;   p += (size_t)NBUCK * 4;
    int* bcur   = (int*)p;   p += (size_t)NBUCK * 4;

    hipMemsetAsync(bcnt, 0, (size_t)NBUCK * 4, stream);

    k_bhist<<<NTILE, 256, 0, stream>>>(ei, bcnt);
    k_bscan<<<1, 512, 0, stream>>>(bcnt, boff, bcur, off);
    k_part<<<NTILE, 256, 0, stream>>>(ei, bcur, pairs);
    k_bsort<<<NBUCK, 256, 0, stream>>>(pairs, bcnt, boff, csr, off);

    k_w1cast<<<(HC * F + 255) / 256, 256, 0, stream>>>(W1, w1x);
    k_wext<<<16, 256, 0, stream>>>(W1, att_src1, att_dst1, w1x);
    k_gemm1<<<(N + 63) / 64, 256, 0, stream>>>(x, w1x, h1m, as1, ad1);
    k_agg1<<<(N + 3) / 4, 256, 0, stream>>>(off, csr, (const unsigned int*)h1m,
                                            as1, ad1, b1, W2, att_src2, att_dst2,
                                            h2b, as2, ad2);

    k_agg2<<<(N + 15) / 16, 256, 0, stream>>>(off, csr, as2, ad2, h2b, b2, outp);
}

// Round 16
// 256.911 us; speedup vs baseline: 1.5876x; 1.0396x over previous
//
#include <hip/hip_runtime.h>
#include <hip/hip_bf16.h>
#include <stdint.h>

constexpr int N     = 100000;
constexpr int E     = 1600000;
constexpr int ETOT  = E + N;
constexpr int F     = 256;
constexpr int H     = 8;
constexpr int C     = 16;
constexpr int HC    = H * C;      // 128
constexpr int NCLS  = 16;
constexpr float NEG_SLOPE = 0.2f;

constexpr int BSHIFT = 8;                       // 256 dsts per bucket
constexpr int NBUCK  = (N + 255) >> BSHIFT;     // 391
constexpr int BCAP   = 8192;
constexpr int TILE   = 16384;
constexpr int NTILE  = (ETOT + TILE - 1) / TILE;

typedef __attribute__((ext_vector_type(8))) short short8;
typedef __attribute__((ext_vector_type(4))) float f32x4;
typedef __attribute__((ext_vector_type(2))) float f32x2;
typedef __attribute__((ext_vector_type(4))) unsigned int u32x4;

__device__ inline unsigned short f2bf(float f) {
    union { float f; unsigned int u; } v{f};
    unsigned int r = v.u + 0x7FFF + ((v.u >> 16) & 1);   // RNE
    return (unsigned short)(r >> 16);
}
__device__ inline float bf2f(unsigned short s) {
    union { unsigned int u; float f; } v{(unsigned int)s << 16};
    return v.f;
}
__device__ inline unsigned char f2fp8(float v) {
    return (unsigned char)(__builtin_amdgcn_cvt_pk_fp8_f32(v, v, 0, false) & 0xff);
}

// ---------------- CSR build: LDS-staged two-level counting sort (proven chain) ----

__global__ __launch_bounds__(256) void k_bhist(const int* __restrict__ ei,
                                               int* __restrict__ bcnt) {
    __shared__ int h[NBUCK];
    for (int i = threadIdx.x; i < NBUCK; i += 256) h[i] = 0;
    __syncthreads();
    int t0 = blockIdx.x * TILE;
    int t1 = (t0 + TILE < ETOT) ? t0 + TILE : ETOT;
    for (int e = t0 + threadIdx.x; e < t1; e += 256) {
        int d = (e < E) ? ei[E + e] : (e - E);
        atomicAdd(&h[d >> BSHIFT], 1);
    }
    __syncthreads();
    for (int i = threadIdx.x; i < NBUCK; i += 256) {
        int c = h[i];
        if (c) atomicAdd(&bcnt[i], c);
    }
}

__global__ void k_bscan(const int* __restrict__ bcnt, int* __restrict__ boff,
                        int* __restrict__ bcur, int* __restrict__ off) {
    __shared__ int s[512];
    int tid = threadIdx.x;
    int v = (tid < NBUCK) ? bcnt[tid] : 0;
    s[tid] = v; __syncthreads();
    for (int ofs = 1; ofs < 512; ofs <<= 1) {
        int t = (tid >= ofs) ? s[tid - ofs] : 0;
        __syncthreads();
        s[tid] += t;
        __syncthreads();
    }
    if (tid < NBUCK) { int ex = s[tid] - v; boff[tid] = ex; bcur[tid] = ex; }
    if (tid == 0) off[N] = ETOT;
}

__global__ __launch_bounds__(256) void k_part(const int* __restrict__ ei,
                                              int* __restrict__ bcur,
                                              unsigned int* __restrict__ pairs) {
    __shared__ int h[NBUCK];
    __shared__ int base[NBUCK];
    int t0 = blockIdx.x * TILE;
    int t1 = (t0 + TILE < ETOT) ? t0 + TILE : ETOT;
    for (int i = threadIdx.x; i < NBUCK; i += 256) h[i] = 0;
    __syncthreads();
    for (int e = t0 + threadIdx.x; e < t1; e += 256) {
        int d = (e < E) ? ei[E + e] : (e - E);
        atomicAdd(&h[d >> BSHIFT], 1);
    }
    __syncthreads();
    for (int i = threadIdx.x; i < NBUCK; i += 256) {
        int c = h[i];
        base[i] = c ? atomicAdd(&bcur[i], c) : 0;
    }
    __syncthreads();
    for (int i = threadIdx.x; i < NBUCK; i += 256) h[i] = 0;
    __syncthreads();
    for (int e = t0 + threadIdx.x; e < t1; e += 256) {
        int s, d;
        if (e < E) { s = ei[e]; d = ei[E + e]; } else { s = e - E; d = s; }
        int b = d >> BSHIFT;
        int r = atomicAdd(&h[b], 1);
        pairs[base[b] + r] = ((unsigned)s << 8) | (unsigned)(d & 255);
    }
}

__global__ __launch_bounds__(256) void k_bsort(const unsigned int* __restrict__ pairs,
                                               const int* __restrict__ bcnt,
                                               const int* __restrict__ boff,
                                               int* __restrict__ csr,
                                               int* __restrict__ off) {
    __shared__ int srcs[BCAP];
    __shared__ int csrs[BCAP];
    __shared__ unsigned char dl[BCAP];
    __shared__ int hist[256];
    __shared__ int sc[256];
    int b = blockIdx.x;
    int nb = bcnt[b]; if (nb > BCAP) nb = BCAP;
    int base = boff[b];
    int dbase = b << BSHIFT;
    int ndst = (N - dbase < 256) ? (N - dbase) : 256;
    int tid = threadIdx.x;

    for (int i = tid; i < nb; i += 256) {
        unsigned int p = pairs[base + i];
        srcs[i] = (int)(p >> 8);
        dl[i] = (unsigned char)(p & 255);
    }
    hist[tid] = 0;
    __syncthreads();
    for (int i = tid; i < nb; i += 256) atomicAdd(&hist[dl[i]], 1);
    __syncthreads();
    int v = hist[tid];
    sc[tid] = v;
    __syncthreads();
    for (int ofs = 1; ofs < 256; ofs <<= 1) {
        int t = (tid >= ofs) ? sc[tid - ofs] : 0;
        __syncthreads();
        sc[tid] += t;
        __syncthreads();
    }
    int lo = sc[tid] - v;
    if (tid < ndst) off[dbase + tid] = base + lo;
    hist[tid] = lo;
    __syncthreads();
    for (int i = tid; i < nb; i += 256) {
        int r = atomicAdd(&hist[dl[i]], 1);
        csrs[r] = srcs[i];
    }
    __syncthreads();
    for (int i = tid; i < nb; i += 256) csr[base + i] = csrs[i];
}

// ---------------- weight prep: w1x rows 0..127 = bf16(W1); 128..143 = score cols

__global__ void k_w1cast(const float* __restrict__ W1, unsigned short* __restrict__ w1x) {
    int i = blockIdx.x * 256 + threadIdx.x;
    if (i < HC * F) w1x[i] = f2bf(W1[i]);
}

__global__ void k_wext(const float* __restrict__ W1,
                       const float* __restrict__ aws, const float* __restrict__ awd,
                       unsigned short* __restrict__ w1x) {
    int r = blockIdx.x;          // 0..15: 0-7 src-heads, 8-15 dst-heads
    int k = threadIdx.x;         // 0..255
    int h = r & 7;
    const float* aw = (r < 8) ? aws : awd;
    float acc = 0.f;
#pragma unroll
    for (int c = 0; c < 16; ++c)
        acc += aw[h * 16 + c] * W1[(size_t)(h * 16 + c) * F + k];
    w1x[(size_t)(128 + r) * F + k] = f2bf(acc);
}

// ---------------- gemm1: h1f[fp8] = bf16(x)@bf16(W1)^T, fused att scores ------

__global__ __launch_bounds__(256) void k_gemm1(const float* __restrict__ x,
                                               const unsigned short* __restrict__ w1x,
                                               unsigned char* __restrict__ h1f,
                                               float* __restrict__ as1,
                                               float* __restrict__ ad1) {
    __shared__ unsigned short Ws[HC * F];  // 64KB, XOR-swizzled 16B chunks (rows 0..127)
    for (int i = threadIdx.x; i < 4096; i += 256) {
        int row = i >> 5;
        int c16 = i & 31;
        u32x4 v = ((const u32x4*)w1x)[i];
        int byte = row * 512 + ((c16 * 16) ^ ((row & 7) << 4));
        *((u32x4*)((char*)Ws + byte)) = v;
    }
    __syncthreads();

    int wid = threadIdx.x >> 6, lane = threadIdx.x & 63;
    int r16 = lane & 15, g = lane >> 4;
    int m = blockIdx.x * 64 + wid * 16 + r16;
    int mc = (m < N) ? m : (N - 1);
    const float* xr = x + (size_t)mc * F;
    const unsigned short* wext = w1x + (size_t)(128 + r16) * F;

    f32x4 acc[9];
#pragma unroll
    for (int nf = 0; nf < 9; ++nf) acc[nf] = (f32x4){0.f, 0.f, 0.f, 0.f};

#pragma unroll
    for (int kk = 0; kk < 8; ++kk) {
        f32x4 a0 = *((const f32x4*)(xr + kk * 32 + g * 8));
        f32x4 a1 = *((const f32x4*)(xr + kk * 32 + g * 8 + 4));
        short8 af;
#pragma unroll
        for (int j = 0; j < 4; ++j) {
            af[j]     = (short)f2bf(a0[j]);
            af[4 + j] = (short)f2bf(a1[j]);
        }
        int kbyte = kk * 64 + g * 16;
#pragma unroll
        for (int nf = 0; nf < 8; ++nf) {
            int row = nf * 16 + r16;
            int byte = row * 512 + (kbyte ^ ((row & 7) << 4));
            short8 bf = *((const short8*)((const char*)Ws + byte));
            acc[nf] = __builtin_amdgcn_mfma_f32_16x16x32_bf16(af, bf, acc[nf], 0, 0, 0);
        }
        short8 bfx = *((const short8*)(wext + kk * 32 + g * 8));
        acc[8] = __builtin_amdgcn_mfma_f32_16x16x32_bf16(af, bfx, acc[8], 0, 0, 0);
    }

    int orow = blockIdx.x * 64 + wid * 16 + g * 4;
#pragma unroll
    for (int j = 0; j < 4; ++j) {
        int rr = orow + j;
        if (rr >= N) continue;
        unsigned char* dst = h1f + (size_t)rr * HC + r16;
#pragma unroll
        for (int nf = 0; nf < 8; ++nf) dst[nf * 16] = f2fp8(acc[nf][j]);
        float v = acc[8][j];
        if (r16 < 8) as1[rr * 8 + r16] = v;
        else         ad1[rr * 8 + (r16 - 8)] = v;
    }
}

// ---- layer 1 aggregate + FUSED layer-2 GEMM + att scores (R10 structure, fp8) ----
// 4 slots (g=l>>4) x 16 lanes (c8=l&15, 8 fp8 channels = 8B per lane).

__global__ __launch_bounds__(256) void k_agg1(const int* __restrict__ off,
                                              const int* __restrict__ csr,
                                              const unsigned int* __restrict__ h1w,
                                              const float* __restrict__ as1,
                                              const float* __restrict__ ad1,
                                              const float* __restrict__ b1,
                                              const float* __restrict__ W2,
                                              const float* __restrict__ aw_s2,
                                              const float* __restrict__ aw_d2,
                                              unsigned short* __restrict__ h2b,
                                              float* __restrict__ as2,
                                              float* __restrict__ ad2) {
    __shared__ float W2s[128 * 17];   // [ (q*16+c8)*17 + j ], 8.5KB
    for (int i = threadIdx.x; i < HC * NCLS; i += 256) {
        int j = i >> 7, k = i & 127;               // i = j*128 + k
        int c8 = k >> 3, q = k & 7;
        W2s[(q * 16 + c8) * 17 + j] = W2[i];
    }
    __syncthreads();

    int w = threadIdx.x >> 6, l = threadIdx.x & 63;
    int n = blockIdx.x * 4 + w;
    if (n >= N) return;
    int g  = l >> 4;            // edge slot 0..3
    int c8 = l & 15;            // channel block (8 fp8)
    int hh = c8 >> 1;           // head of this block
    unsigned int wb = (unsigned int)(c8 * 2);   // word offset into 32-word record
    int e0 = off[n], e1 = off[n + 1];
    int deg = e1 - e0;
    float adst = ad1[n * 8 + hh];
    float den = 0.f;
    float acc[8] = {0.f, 0.f, 0.f, 0.f, 0.f, 0.f, 0.f, 0.f};

    int eb = 0;
    for (; eb + 8 <= deg; eb += 8) {
        int sA = csr[e0 + eb + g];
        int sB = csr[e0 + eb + 4 + g];
        float avA = as1[sA * 8 + hh];
        float avB = as1[sB * 8 + hh];
        uint2 vA = *((const uint2*)(h1w + ((unsigned int)sA << 5) + wb));
        uint2 vB = *((const uint2*)(h1w + ((unsigned int)sB << 5) + wb));
        float aA = avA + adst; aA = fmaxf(aA, aA * NEG_SLOPE);
        float aB = avB + adst; aB = fmaxf(aB, aB * NEG_SLOPE);
        float wA = __expf(aA), wB = __expf(aB);
        den += wA + wB;
        f32x2 a01 = __builtin_amdgcn_cvt_pk_f32_fp8(vA.x, false);
        f32x2 a23 = __builtin_amdgcn_cvt_pk_f32_fp8(vA.x, true);
        f32x2 a45 = __builtin_amdgcn_cvt_pk_f32_fp8(vA.y, false);
        f32x2 a67 = __builtin_amdgcn_cvt_pk_f32_fp8(vA.y, true);
        f32x2 b01 = __builtin_amdgcn_cvt_pk_f32_fp8(vB.x, false);
        f32x2 b23 = __builtin_amdgcn_cvt_pk_f32_fp8(vB.x, true);
        f32x2 b45 = __builtin_amdgcn_cvt_pk_f32_fp8(vB.y, false);
        f32x2 b67 = __builtin_amdgcn_cvt_pk_f32_fp8(vB.y, true);
        acc[0] += wA * a01[0] + wB * b01[0];
        acc[1] += wA * a01[1] + wB * b01[1];
        acc[2] += wA * a23[0] + wB * b23[0];
        acc[3] += wA * a23[1] + wB * b23[1];
        acc[4] += wA * a45[0] + wB * b45[0];
        acc[5] += wA * a45[1] + wB * b45[1];
        acc[6] += wA * a67[0] + wB * b67[0];
        acc[7] += wA * a67[1] + wB * b67[1];
    }
    for (; eb < deg; eb += 4) {
        int slot = eb + g;
        bool ok = slot < deg;
        int s = csr[e0 + (ok ? slot : 0)];
        float aval = as1[s * 8 + hh];
        uint2 v = *((const uint2*)(h1w + ((unsigned int)s << 5) + wb));
        float al = aval + adst; al = fmaxf(al, al * NEG_SLOPE);
        float wt = ok ? __expf(al) : 0.f;
        den += wt;
        f32x2 a01 = __builtin_amdgcn_cvt_pk_f32_fp8(v.x, false);
        f32x2 a23 = __builtin_amdgcn_cvt_pk_f32_fp8(v.x, true);
        f32x2 a45 = __builtin_amdgcn_cvt_pk_f32_fp8(v.y, false);
        f32x2 a67 = __builtin_amdgcn_cvt_pk_f32_fp8(v.y, true);
        acc[0] += wt * a01[0];
        acc[1] += wt * a01[1];
        acc[2] += wt * a23[0];
        acc[3] += wt * a23[1];
        acc[4] += wt * a45[0];
        acc[5] += wt * a45[1];
        acc[6] += wt * a67[0];
        acc[7] += wt * a67[1];
    }
    // reduce over the 4 edge slots (lane bits 4,5) -> ALL lanes hold the sums
#pragma unroll
    for (int q = 0; q < 8; ++q) {
        acc[q] += __shfl_xor(acc[q], 16, 64);
        acc[q] += __shfl_xor(acc[q], 32, 64);
    }
    den += __shfl_xor(den, 16, 64);
    den += __shfl_xor(den, 32, 64);

    // ---- fused epilogue (all 64 lanes) ----
    float inv = 1.f / (den + 1e-16f);
    float v8[8];
#pragma unroll
    for (int q = 0; q < 8; ++q) {
        float v = acc[q] * inv + b1[c8 * 8 + q];
        v8[q] = (v > 0.f) ? v : (__expf(v) - 1.f);   // ELU: out1 channel c8*8+q
    }
    // gemm2 partials: lane covers channels c8*8+q, classes g*4..g*4+3
    float p0 = 0.f, p1 = 0.f, p2 = 0.f, p3 = 0.f;
#pragma unroll
    for (int q = 0; q < 8; ++q) {
        const float* wr = &W2s[(q * 16 + c8) * 17 + g * 4];
        p0 += v8[q] * wr[0];
        p1 += v8[q] * wr[1];
        p2 += v8[q] * wr[2];
        p3 += v8[q] * wr[3];
    }
    // butterfly over c8 (bits 0..3): all lanes in slot g hold h2[g*4+0..3]
#pragma unroll
    for (int msk = 8; msk >= 1; msk >>= 1) {
        p0 += __shfl_xor(p0, msk, 64);
        p1 += __shfl_xor(p1, msk, 64);
        p2 += __shfl_xor(p2, msk, 64);
        p3 += __shfl_xor(p3, msk, 64);
    }
    // att scores for layer 2
    float sa = p0 * aw_s2[g * 4] + p1 * aw_s2[g * 4 + 1]
             + p2 * aw_s2[g * 4 + 2] + p3 * aw_s2[g * 4 + 3];
    float da = p0 * aw_d2[g * 4] + p1 * aw_d2[g * 4 + 1]
             + p2 * aw_d2[g * 4 + 2] + p3 * aw_d2[g * 4 + 3];
    sa += __shfl_xor(sa, 16, 64); sa += __shfl_xor(sa, 32, 64);
    da += __shfl_xor(da, 16, 64); da += __shfl_xor(da, 32, 64);
    if (l == 0) { as2[n] = sa; ad2[n] = da; }
    if (c8 < 4) {
        float h2v = p0;
        h2v = (c8 == 1) ? p1 : h2v;
        h2v = (c8 == 2) ? p2 : h2v;
        h2v = (c8 == 3) ? p3 : h2v;
        h2b[(size_t)n * NCLS + g * 4 + c8] = f2bf(h2v);
    }
}

// ---------------- layer 2 aggregate (bf16 gather, unrolled x4) + log_softmax ----

__global__ __launch_bounds__(256) void k_agg2(const int* __restrict__ off,
                                              const int* __restrict__ csr,
                                              const float* __restrict__ as2,
                                              const float* __restrict__ ad2,
                                              const unsigned short* __restrict__ h2b,
                                              const float* __restrict__ b2,
                                              float* __restrict__ outp) {
    int gpos = threadIdx.x >> 4, c = threadIdx.x & 15;
    int n = blockIdx.x * 16 + gpos;
    if (n >= N) return;
    int e0 = off[n], e1 = off[n + 1];
    float adst = ad2[n];
    float den = 0.f, acc = 0.f;
    int e = e0;
    for (; e + 4 <= e1; e += 4) {
        int s0 = csr[e], s1 = csr[e + 1], s2 = csr[e + 2], s3 = csr[e + 3];
        float x0 = as2[s0], x1 = as2[s1], x2 = as2[s2], x3 = as2[s3];
        unsigned short m0 = h2b[s0 * NCLS + c], m1 = h2b[s1 * NCLS + c];
        unsigned short m2 = h2b[s2 * NCLS + c], m3 = h2b[s3 * NCLS + c];
        float a0 = x0 + adst; a0 = fmaxf(a0, a0 * NEG_SLOPE);
        float a1 = x1 + adst; a1 = fmaxf(a1, a1 * NEG_SLOPE);
        float a2 = x2 + adst; a2 = fmaxf(a2, a2 * NEG_SLOPE);
        float a3 = x3 + adst; a3 = fmaxf(a3, a3 * NEG_SLOPE);
        float w0 = __expf(a0), w1 = __expf(a1), w2 = __expf(a2), w3 = __expf(a3);
        den += (w0 + w1) + (w2 + w3);
        acc += w0 * bf2f(m0) + w1 * bf2f(m1) + w2 * bf2f(m2) + w3 * bf2f(m3);
    }
    for (; e < e1; ++e) {
        int s = csr[e];
        float al = as2[s] + adst;
        al = fmaxf(al, al * NEG_SLOPE);
        float wt = __expf(al);
        den += wt;
        acc += wt * bf2f(h2b[s * NCLS + c]);
    }
    float v = acc / (den + 1e-16f) + b2[c];
    float mx = v;
#pragma unroll
    for (int msk = 8; msk >= 1; msk >>= 1) mx = fmaxf(mx, __shfl_xor(mx, msk, 64));
    float ex = __expf(v - mx), se = ex;
#pragma unroll
    for (int msk = 8; msk >= 1; msk >>= 1) se += __shfl_xor(se, msk, 64);
    outp[n * NCLS + c] = v - mx - __logf(se);
}

// ---------------- launch ----------------

extern "C" void kernel_launch(void* const* d_in, const int* in_sizes, int n_in,
                              void* d_out, int out_size, void* d_ws, size_t ws_size,
                              hipStream_t stream) {
    const float* x        = (const float*)d_in[0];
    const int*   ei       = (const int*)d_in[1];
    const float* W1       = (const float*)d_in[2];
    const float* att_src1 = (const float*)d_in[3];
    const float* att_dst1 = (const float*)d_in[4];
    const float* b1       = (const float*)d_in[5];
    const float* W2       = (const float*)d_in[6];
    const float* att_src2 = (const float*)d_in[7];
    const float* att_dst2 = (const float*)d_in[8];
    const float* b2       = (const float*)d_in[9];
    float* outp = (float*)d_out;

    char* p = (char*)d_ws;
    unsigned char* h1f    = (unsigned char*)p;  p += (size_t)N * HC;       // 12.8MB fp8
    unsigned short* h2b   = (unsigned short*)p; p += (size_t)N * NCLS * 2; // 3.2MB
    float* as1  = (float*)p; p += (size_t)N * H * 4;                       // 3.2MB
    float* ad1  = (float*)p; p += (size_t)N * H * 4;                       // 3.2MB
    float* as2  = (float*)p; p += (size_t)N * 4;
    float* ad2  = (float*)p; p += (size_t)N * 4;
    unsigned short* w1x = (unsigned short*)p; p += (size_t)144 * F * 2;    // 73.7KB
    unsigned int* pairs = (unsigned int*)p; p += (size_t)ETOT * 4;         // 6.8MB
    int* csr    = (int*)p;   p += (size_t)ETOT * 4;
    int* off    = (int*)p;   p += (size_t)(N + 1) * 4;
    int* bcnt   = (int*)p;   p += (size_t)NBUCK * 4;
    int* boff   = (int*)p;   p += (size_t)NBUCK * 4;
    int* bcur   = (int*)p;   p += (size_t)NBUCK * 4;

    hipMemsetAsync(bcnt, 0, (size_t)NBUCK * 4, stream);

    k_bhist<<<NTILE, 256, 0, stream>>>(ei, bcnt);
    k_bscan<<<1, 512, 0, stream>>>(bcnt, boff, bcur, off);
    k_part<<<NTILE, 256, 0, stream>>>(ei, bcur, pairs);
    k_bsort<<<NBUCK, 256, 0, stream>>>(pairs, bcnt, boff, csr, off);

    k_w1cast<<<(HC * F + 255) / 256, 256, 0, stream>>>(W1, w1x);
    k_wext<<<16, 256, 0, stream>>>(W1, att_src1, att_dst1, w1x);
    k_gemm1<<<(N + 63) / 64, 256, 0, stream>>>(x, w1x, h1f, as1, ad1);
    k_agg1<<<(N + 3) / 4, 256, 0, stream>>>(off, csr, (const unsigned int*)h1f,
                                            as1, ad1, b1, W2, att_src2, att_dst2,
                                            h2b, as2, ad2);

    k_agg2<<<(N + 15) / 16, 256, 0, stream>>>(off, csr, as2, ad2, h2b, b2, outp);
}

// Round 17
// 222.360 us; speedup vs baseline: 1.8343x; 1.1554x over previous
//
#include <hip/hip_runtime.h>
#include <hip/hip_bf16.h>
#include <stdint.h>

constexpr int N     = 100000;
constexpr int E     = 1600000;
constexpr int ETOT  = E + N;
constexpr int F     = 256;
constexpr int H     = 8;
constexpr int C     = 16;
constexpr int HC    = H * C;      // 128
constexpr int NCLS  = 16;
constexpr float NEG_SLOPE = 0.2f;

constexpr int BSHIFT = 8;                       // 256 dsts per bucket
constexpr int NBUCK  = (N + 255) >> BSHIFT;     // 391
constexpr int BCAP   = 8192;
constexpr int TILE   = 16384;
constexpr int NTILE  = (ETOT + TILE - 1) / TILE;   // 104

typedef __attribute__((ext_vector_type(8))) short short8;
typedef __attribute__((ext_vector_type(4))) float f32x4;
typedef __attribute__((ext_vector_type(2))) float f32x2;
typedef __attribute__((ext_vector_type(4))) unsigned int u32x4;

__device__ inline unsigned short f2bf(float f) {
    union { float f; unsigned int u; } v{f};
    unsigned int r = v.u + 0x7FFF + ((v.u >> 16) & 1);   // RNE
    return (unsigned short)(r >> 16);
}
__device__ inline float bf2f(unsigned short s) {
    union { unsigned int u; float f; } v{(unsigned int)s << 16};
    return v.f;
}
__device__ inline unsigned char f2fp8(float v) {
    return (unsigned char)(__builtin_amdgcn_cvt_pk_fp8_f32(v, v, 0, false) & 0xff);
}

// ---- fused pre-pass: bhist (blocks 0..NTILE-1) | w1cast (next 128) | wext (next 16)

__global__ __launch_bounds__(256) void k_pre(const int* __restrict__ ei,
                                             int* __restrict__ bcnt,
                                             const float* __restrict__ W1,
                                             const float* __restrict__ aws,
                                             const float* __restrict__ awd,
                                             unsigned short* __restrict__ w1x) {
    __shared__ int h[NBUCK];
    int b = blockIdx.x;
    if (b < NTILE) {
        // ---- bhist ----
        for (int i = threadIdx.x; i < NBUCK; i += 256) h[i] = 0;
        __syncthreads();
        int t0 = b * TILE;
        int t1 = (t0 + TILE < ETOT) ? t0 + TILE : ETOT;
        for (int e = t0 + threadIdx.x; e < t1; e += 256) {
            int d = (e < E) ? ei[E + e] : (e - E);
            atomicAdd(&h[d >> BSHIFT], 1);
        }
        __syncthreads();
        for (int i = threadIdx.x; i < NBUCK; i += 256) {
            int c = h[i];
            if (c) atomicAdd(&bcnt[i], c);
        }
    } else if (b < NTILE + 128) {
        // ---- w1cast ----
        int i = (b - NTILE) * 256 + threadIdx.x;
        if (i < HC * F) w1x[i] = f2bf(W1[i]);
    } else {
        // ---- wext ----
        int r = b - NTILE - 128;     // 0..15
        int k = threadIdx.x;
        int hh = r & 7;
        const float* aw = (r < 8) ? aws : awd;
        float acc = 0.f;
#pragma unroll
        for (int c = 0; c < 16; ++c)
            acc += aw[hh * 16 + c] * W1[(size_t)(hh * 16 + c) * F + k];
        w1x[(size_t)(128 + r) * F + k] = f2bf(acc);
    }
}

__global__ void k_bscan(const int* __restrict__ bcnt, int* __restrict__ boff,
                        int* __restrict__ bcur, int* __restrict__ off) {
    __shared__ int s[512];
    int tid = threadIdx.x;
    int v = (tid < NBUCK) ? bcnt[tid] : 0;
    s[tid] = v; __syncthreads();
    for (int ofs = 1; ofs < 512; ofs <<= 1) {
        int t = (tid >= ofs) ? s[tid - ofs] : 0;
        __syncthreads();
        s[tid] += t;
        __syncthreads();
    }
    if (tid < NBUCK) { int ex = s[tid] - v; boff[tid] = ex; bcur[tid] = ex; }
    if (tid == 0) off[N] = ETOT;
}

// ---- fused mid-pass: part (blocks 0..NTILE-1) | gemm1 (rest) ----

__global__ __launch_bounds__(256) void k_mid(const int* __restrict__ ei,
                                             int* __restrict__ bcur,
                                             unsigned int* __restrict__ pairs,
                                             const float* __restrict__ x,
                                             const unsigned short* __restrict__ w1x,
                                             unsigned char* __restrict__ h1f,
                                             float* __restrict__ as1,
                                             float* __restrict__ ad1) {
    __shared__ char smem[65536];
    if (blockIdx.x < NTILE) {
        // ---- part ----
        int* h    = (int*)smem;
        int* base = h + NBUCK;
        int t0 = blockIdx.x * TILE;
        int t1 = (t0 + TILE < ETOT) ? t0 + TILE : ETOT;
        for (int i = threadIdx.x; i < NBUCK; i += 256) h[i] = 0;
        __syncthreads();
        for (int e = t0 + threadIdx.x; e < t1; e += 256) {
            int d = (e < E) ? ei[E + e] : (e - E);
            atomicAdd(&h[d >> BSHIFT], 1);
        }
        __syncthreads();
        for (int i = threadIdx.x; i < NBUCK; i += 256) {
            int c = h[i];
            base[i] = c ? atomicAdd(&bcur[i], c) : 0;
        }
        __syncthreads();
        for (int i = threadIdx.x; i < NBUCK; i += 256) h[i] = 0;
        __syncthreads();
        for (int e = t0 + threadIdx.x; e < t1; e += 256) {
            int s, d;
            if (e < E) { s = ei[e]; d = ei[E + e]; } else { s = e - E; d = s; }
            int b = d >> BSHIFT;
            int r = atomicAdd(&h[b], 1);
            pairs[base[b] + r] = ((unsigned)s << 8) | (unsigned)(d & 255);
        }
        return;
    }
    // ---- gemm1 ----
    unsigned short* Ws = (unsigned short*)smem;   // 64KB XOR-swizzled
    int bid = blockIdx.x - NTILE;
    for (int i = threadIdx.x; i < 4096; i += 256) {
        int row = i >> 5;
        int c16 = i & 31;
        u32x4 v = ((const u32x4*)w1x)[i];
        int byte = row * 512 + ((c16 * 16) ^ ((row & 7) << 4));
        *((u32x4*)((char*)Ws + byte)) = v;
    }
    __syncthreads();

    int wid = threadIdx.x >> 6, lane = threadIdx.x & 63;
    int r16 = lane & 15, g = lane >> 4;
    int m = bid * 64 + wid * 16 + r16;
    int mc = (m < N) ? m : (N - 1);
    const float* xr = x + (size_t)mc * F;
    const unsigned short* wext = w1x + (size_t)(128 + r16) * F;

    f32x4 acc[9];
#pragma unroll
    for (int nf = 0; nf < 9; ++nf) acc[nf] = (f32x4){0.f, 0.f, 0.f, 0.f};

#pragma unroll
    for (int kk = 0; kk < 8; ++kk) {
        f32x4 a0 = *((const f32x4*)(xr + kk * 32 + g * 8));
        f32x4 a1 = *((const f32x4*)(xr + kk * 32 + g * 8 + 4));
        short8 af;
#pragma unroll
        for (int j = 0; j < 4; ++j) {
            af[j]     = (short)f2bf(a0[j]);
            af[4 + j] = (short)f2bf(a1[j]);
        }
        int kbyte = kk * 64 + g * 16;
#pragma unroll
        for (int nf = 0; nf < 8; ++nf) {
            int row = nf * 16 + r16;
            int byte = row * 512 + (kbyte ^ ((row & 7) << 4));
            short8 bf = *((const short8*)((const char*)Ws + byte));
            acc[nf] = __builtin_amdgcn_mfma_f32_16x16x32_bf16(af, bf, acc[nf], 0, 0, 0);
        }
        short8 bfx = *((const short8*)(wext + kk * 32 + g * 8));
        acc[8] = __builtin_amdgcn_mfma_f32_16x16x32_bf16(af, bfx, acc[8], 0, 0, 0);
    }

    int orow = bid * 64 + wid * 16 + g * 4;
#pragma unroll
    for (int j = 0; j < 4; ++j) {
        int rr = orow + j;
        if (rr >= N) continue;
        unsigned char* dst = h1f + (size_t)rr * HC + r16;
#pragma unroll
        for (int nf = 0; nf < 8; ++nf) dst[nf * 16] = f2fp8(acc[nf][j]);
        float v = acc[8][j];
        if (r16 < 8) as1[rr * 8 + r16] = v;
        else         ad1[rr * 8 + (r16 - 8)] = v;
    }
}

__global__ __launch_bounds__(256) void k_bsort(const unsigned int* __restrict__ pairs,
                                               const int* __restrict__ bcnt,
                                               const int* __restrict__ boff,
                                               int* __restrict__ csr,
                                               int* __restrict__ off) {
    __shared__ int srcs[BCAP];
    __shared__ int csrs[BCAP];
    __shared__ unsigned char dl[BCAP];
    __shared__ int hist[256];
    __shared__ int sc[256];
    int b = blockIdx.x;
    int nb = bcnt[b]; if (nb > BCAP) nb = BCAP;
    int base = boff[b];
    int dbase = b << BSHIFT;
    int ndst = (N - dbase < 256) ? (N - dbase) : 256;
    int tid = threadIdx.x;

    for (int i = tid; i < nb; i += 256) {
        unsigned int p = pairs[base + i];
        srcs[i] = (int)(p >> 8);
        dl[i] = (unsigned char)(p & 255);
    }
    hist[tid] = 0;
    __syncthreads();
    for (int i = tid; i < nb; i += 256) atomicAdd(&hist[dl[i]], 1);
    __syncthreads();
    int v = hist[tid];
    sc[tid] = v;
    __syncthreads();
    for (int ofs = 1; ofs < 256; ofs <<= 1) {
        int t = (tid >= ofs) ? sc[tid - ofs] : 0;
        __syncthreads();
        sc[tid] += t;
        __syncthreads();
    }
    int lo = sc[tid] - v;
    if (tid < ndst) off[dbase + tid] = base + lo;
    hist[tid] = lo;
    __syncthreads();
    for (int i = tid; i < nb; i += 256) {
        int r = atomicAdd(&hist[dl[i]], 1);
        csrs[r] = srcs[i];
    }
    __syncthreads();
    for (int i = tid; i < nb; i += 256) csr[base + i] = csrs[i];
}

// ---- layer 1 aggregate + FUSED layer-2 GEMM + att scores (R16 proven, fp8) ----

__global__ __launch_bounds__(256) void k_agg1(const int* __restrict__ off,
                                              const int* __restrict__ csr,
                                              const unsigned int* __restrict__ h1w,
                                              const float* __restrict__ as1,
                                              const float* __restrict__ ad1,
                                              const float* __restrict__ b1,
                                              const float* __restrict__ W2,
                                              const float* __restrict__ aw_s2,
                                              const float* __restrict__ aw_d2,
                                              unsigned short* __restrict__ h2b,
                                              float* __restrict__ as2,
                                              float* __restrict__ ad2) {
    __shared__ float W2s[128 * 17];   // [ (q*16+c8)*17 + j ], 8.5KB
    for (int i = threadIdx.x; i < HC * NCLS; i += 256) {
        int j = i >> 7, k = i & 127;               // i = j*128 + k
        int c8 = k >> 3, q = k & 7;
        W2s[(q * 16 + c8) * 17 + j] = W2[i];
    }
    __syncthreads();

    int w = threadIdx.x >> 6, l = threadIdx.x & 63;
    int n = blockIdx.x * 4 + w;
    if (n >= N) return;
    int g  = l >> 4;            // edge slot 0..3
    int c8 = l & 15;            // channel block (8 fp8)
    int hh = c8 >> 1;           // head of this block
    unsigned int wb = (unsigned int)(c8 * 2);   // word offset into 32-word record
    int e0 = off[n], e1 = off[n + 1];
    int deg = e1 - e0;
    float adst = ad1[n * 8 + hh];
    float den = 0.f;
    float acc[8] = {0.f, 0.f, 0.f, 0.f, 0.f, 0.f, 0.f, 0.f};

    int eb = 0;
    for (; eb + 8 <= deg; eb += 8) {
        int sA = csr[e0 + eb + g];
        int sB = csr[e0 + eb + 4 + g];
        float avA = as1[sA * 8 + hh];
        float avB = as1[sB * 8 + hh];
        uint2 vA = *((const uint2*)(h1w + ((unsigned int)sA << 5) + wb));
        uint2 vB = *((const uint2*)(h1w + ((unsigned int)sB << 5) + wb));
        float aA = avA + adst; aA = fmaxf(aA, aA * NEG_SLOPE);
        float aB = avB + adst; aB = fmaxf(aB, aB * NEG_SLOPE);
        float wA = __expf(aA), wB = __expf(aB);
        den += wA + wB;
        f32x2 a01 = __builtin_amdgcn_cvt_pk_f32_fp8(vA.x, false);
        f32x2 a23 = __builtin_amdgcn_cvt_pk_f32_fp8(vA.x, true);
        f32x2 a45 = __builtin_amdgcn_cvt_pk_f32_fp8(vA.y, false);
        f32x2 a67 = __builtin_amdgcn_cvt_pk_f32_fp8(vA.y, true);
        f32x2 b01 = __builtin_amdgcn_cvt_pk_f32_fp8(vB.x, false);
        f32x2 b23 = __builtin_amdgcn_cvt_pk_f32_fp8(vB.x, true);
        f32x2 b45 = __builtin_amdgcn_cvt_pk_f32_fp8(vB.y, false);
        f32x2 b67 = __builtin_amdgcn_cvt_pk_f32_fp8(vB.y, true);
        acc[0] += wA * a01[0] + wB * b01[0];
        acc[1] += wA * a01[1] + wB * b01[1];
        acc[2] += wA * a23[0] + wB * b23[0];
        acc[3] += wA * a23[1] + wB * b23[1];
        acc[4] += wA * a45[0] + wB * b45[0];
        acc[5] += wA * a45[1] + wB * b45[1];
        acc[6] += wA * a67[0] + wB * b67[0];
        acc[7] += wA * a67[1] + wB * b67[1];
    }
    for (; eb < deg; eb += 4) {
        int slot = eb + g;
        bool ok = slot < deg;
        int s = csr[e0 + (ok ? slot : 0)];
        float aval = as1[s * 8 + hh];
        uint2 v = *((const uint2*)(h1w + ((unsigned int)s << 5) + wb));
        float al = aval + adst; al = fmaxf(al, al * NEG_SLOPE);
        float wt = ok ? __expf(al) : 0.f;
        den += wt;
        f32x2 a01 = __builtin_amdgcn_cvt_pk_f32_fp8(v.x, false);
        f32x2 a23 = __builtin_amdgcn_cvt_pk_f32_fp8(v.x, true);
        f32x2 a45 = __builtin_amdgcn_cvt_pk_f32_fp8(v.y, false);
        f32x2 a67 = __builtin_amdgcn_cvt_pk_f32_fp8(v.y, true);
        acc[0] += wt * a01[0];
        acc[1] += wt * a01[1];
        acc[2] += wt * a23[0];
        acc[3] += wt * a23[1];
        acc[4] += wt * a45[0];
        acc[5] += wt * a45[1];
        acc[6] += wt * a67[0];
        acc[7] += wt * a67[1];
    }
    // reduce over the 4 edge slots (lane bits 4,5) -> ALL lanes hold the sums
#pragma unroll
    for (int q = 0; q < 8; ++q) {
        acc[q] += __shfl_xor(acc[q], 16, 64);
        acc[q] += __shfl_xor(acc[q], 32, 64);
    }
    den += __shfl_xor(den, 16, 64);
    den += __shfl_xor(den, 32, 64);

    // ---- fused epilogue (all 64 lanes) ----
    float inv = 1.f / (den + 1e-16f);
    float v8[8];
#pragma unroll
    for (int q = 0; q < 8; ++q) {
        float v = acc[q] * inv + b1[c8 * 8 + q];
        v8[q] = (v > 0.f) ? v : (__expf(v) - 1.f);   // ELU: out1 channel c8*8+q
    }
    float p0 = 0.f, p1 = 0.f, p2 = 0.f, p3 = 0.f;
#pragma unroll
    for (int q = 0; q < 8; ++q) {
        const float* wr = &W2s[(q * 16 + c8) * 17 + g * 4];
        p0 += v8[q] * wr[0];
        p1 += v8[q] * wr[1];
        p2 += v8[q] * wr[2];
        p3 += v8[q] * wr[3];
    }
#pragma unroll
    for (int msk = 8; msk >= 1; msk >>= 1) {
        p0 += __shfl_xor(p0, msk, 64);
        p1 += __shfl_xor(p1, msk, 64);
        p2 += __shfl_xor(p2, msk, 64);
        p3 += __shfl_xor(p3, msk, 64);
    }
    float sa = p0 * aw_s2[g * 4] + p1 * aw_s2[g * 4 + 1]
             + p2 * aw_s2[g * 4 + 2] + p3 * aw_s2[g * 4 + 3];
    float da = p0 * aw_d2[g * 4] + p1 * aw_d2[g * 4 + 1]
             + p2 * aw_d2[g * 4 + 2] + p3 * aw_d2[g * 4 + 3];
    sa += __shfl_xor(sa, 16, 64); sa += __shfl_xor(sa, 32, 64);
    da += __shfl_xor(da, 16, 64); da += __shfl_xor(da, 32, 64);
    if (l == 0) { as2[n] = sa; ad2[n] = da; }
    if (c8 < 4) {
        float h2v = p0;
        h2v = (c8 == 1) ? p1 : h2v;
        h2v = (c8 == 2) ? p2 : h2v;
        h2v = (c8 == 3) ? p3 : h2v;
        h2b[(size_t)n * NCLS + g * 4 + c8] = f2bf(h2v);
    }
}

// ---------------- layer 2 aggregate (bf16 gather, unrolled x4) + log_softmax ----

__global__ __launch_bounds__(256) void k_agg2(const int* __restrict__ off,
                                              const int* __restrict__ csr,
                                              const float* __restrict__ as2,
                                              const float* __restrict__ ad2,
                                              const unsigned short* __restrict__ h2b,
                                              const float* __restrict__ b2,
                                              float* __restrict__ outp) {
    int gpos = threadIdx.x >> 4, c = threadIdx.x & 15;
    int n = blockIdx.x * 16 + gpos;
    if (n >= N) return;
    int e0 = off[n], e1 = off[n + 1];
    float adst = ad2[n];
    float den = 0.f, acc = 0.f;
    int e = e0;
    for (; e + 4 <= e1; e += 4) {
        int s0 = csr[e], s1 = csr[e + 1], s2 = csr[e + 2], s3 = csr[e + 3];
        float x0 = as2[s0], x1 = as2[s1], x2 = as2[s2], x3 = as2[s3];
        unsigned short m0 = h2b[s0 * NCLS + c], m1 = h2b[s1 * NCLS + c];
        unsigned short m2 = h2b[s2 * NCLS + c], m3 = h2b[s3 * NCLS + c];
        float a0 = x0 + adst; a0 = fmaxf(a0, a0 * NEG_SLOPE);
        float a1 = x1 + adst; a1 = fmaxf(a1, a1 * NEG_SLOPE);
        float a2 = x2 + adst; a2 = fmaxf(a2, a2 * NEG_SLOPE);
        float a3 = x3 + adst; a3 = fmaxf(a3, a3 * NEG_SLOPE);
        float w0 = __expf(a0), w1 = __expf(a1), w2 = __expf(a2), w3 = __expf(a3);
        den += (w0 + w1) + (w2 + w3);
        acc += w0 * bf2f(m0) + w1 * bf2f(m1) + w2 * bf2f(m2) + w3 * bf2f(m3);
    }
    for (; e < e1; ++e) {
        int s = csr[e];
        float al = as2[s] + adst;
        al = fmaxf(al, al * NEG_SLOPE);
        float wt = __expf(al);
        den += wt;
        acc += wt * bf2f(h2b[s * NCLS + c]);
    }
    float v = acc / (den + 1e-16f) + b2[c];
    float mx = v;
#pragma unroll
    for (int msk = 8; msk >= 1; msk >>= 1) mx = fmaxf(mx, __shfl_xor(mx, msk, 64));
    float ex = __expf(v - mx), se = ex;
#pragma unroll
    for (int msk = 8; msk >= 1; msk >>= 1) se += __shfl_xor(se, msk, 64);
    outp[n * NCLS + c] = v - mx - __logf(se);
}

// ---------------- launch ----------------

extern "C" void kernel_launch(void* const* d_in, const int* in_sizes, int n_in,
                              void* d_out, int out_size, void* d_ws, size_t ws_size,
                              hipStream_t stream) {
    const float* x        = (const float*)d_in[0];
    const int*   ei       = (const int*)d_in[1];
    const float* W1       = (const float*)d_in[2];
    const float* att_src1 = (const float*)d_in[3];
    const float* att_dst1 = (const float*)d_in[4];
    const float* b1       = (const float*)d_in[5];
    const float* W2       = (const float*)d_in[6];
    const float* att_src2 = (const float*)d_in[7];
    const float* att_dst2 = (const float*)d_in[8];
    const float* b2       = (const float*)d_in[9];
    float* outp = (float*)d_out;

    char* p = (char*)d_ws;
    unsigned char* h1f    = (unsigned char*)p;  p += (size_t)N * HC;       // 12.8MB fp8
    unsigned short* h2b   = (unsigned short*)p; p += (size_t)N * NCLS * 2; // 3.2MB
    float* as1  = (float*)p; p += (size_t)N * H * 4;                       // 3.2MB
    float* ad1  = (float*)p; p += (size_t)N * H * 4;                       // 3.2MB
    float* as2  = (float*)p; p += (size_t)N * 4;
    float* ad2  = (float*)p; p += (size_t)N * 4;
    unsigned short* w1x = (unsigned short*)p; p += (size_t)144 * F * 2;    // 73.7KB
    unsigned int* pairs = (unsigned int*)p; p += (size_t)ETOT * 4;         // 6.8MB
    int* csr    = (int*)p;   p += (size_t)ETOT * 4;
    int* off    = (int*)p;   p += (size_t)(N + 1) * 4;
    int* bcnt   = (int*)p;   p += (size_t)NBUCK * 4;
    int* boff   = (int*)p;   p += (size_t)NBUCK * 4;
    int* bcur   = (int*)p;   p += (size_t)NBUCK * 4;

    hipMemsetAsync(bcnt, 0, (size_t)NBUCK * 4, stream);

    k_pre<<<NTILE + 128 + 16, 256, 0, stream>>>(ei, bcnt, W1, att_src1, att_dst1, w1x);
    k_bscan<<<1, 512, 0, stream>>>(bcnt, boff, bcur, off);
    k_mid<<<NTILE + (N + 63) / 64, 256, 0, stream>>>(ei, bcur, pairs,
                                                     x, w1x, h1f, as1, ad1);
    k_bsort<<<NBUCK, 256, 0, stream>>>(pairs, bcnt, boff, csr, off);

    k_agg1<<<(N + 3) / 4, 256, 0, stream>>>(off, csr, (const unsigned int*)h1f,
                                            as1, ad1, b1, W2, att_src2, att_dst2,
                                            h2b, as2, ad2);

    k_agg2<<<(N + 15) / 16, 256, 0, stream>>>(off, csr, as2, ad2, h2b, b2, outp);
}

// Round 18
// 214.035 us; speedup vs baseline: 1.9056x; 1.0389x over previous
//
#include <hip/hip_runtime.h>
#include <hip/hip_bf16.h>
#include <stdint.h>

constexpr int N     = 100000;
constexpr int E     = 1600000;
constexpr int ETOT  = E + N;
constexpr int F     = 256;
constexpr int H     = 8;
constexpr int C     = 16;
constexpr int HC    = H * C;      // 128
constexpr int NCLS  = 16;
constexpr float NEG_SLOPE = 0.2f;

constexpr int BSHIFT = 8;                       // 256 dsts per bucket
constexpr int NBUCK  = (N + 255) >> BSHIFT;     // 391
constexpr int BCAP   = 8192;
constexpr int TILE   = 16384;
constexpr int NTILE  = (ETOT + TILE - 1) / TILE;   // 104

typedef __attribute__((ext_vector_type(8))) short short8;
typedef __attribute__((ext_vector_type(4))) float f32x4;
typedef __attribute__((ext_vector_type(2))) float f32x2;
typedef __attribute__((ext_vector_type(4))) unsigned int u32x4;

__device__ inline unsigned short f2bf(float f) {
    union { float f; unsigned int u; } v{f};
    unsigned int r = v.u + 0x7FFF + ((v.u >> 16) & 1);   // RNE
    return (unsigned short)(r >> 16);
}
__device__ inline float bf2f(unsigned short s) {
    union { unsigned int u; float f; } v{(unsigned int)s << 16};
    return v.f;
}
__device__ inline unsigned char f2fp8(float v) {
    return (unsigned char)(__builtin_amdgcn_cvt_pk_fp8_f32(v, v, 0, false) & 0xff);
}

// ---- fused pre-pass: bhist (blocks 0..NTILE-1) | w1cast (next 128) | wext (next 16)

__global__ __launch_bounds__(256) void k_pre(const int* __restrict__ ei,
                                             int* __restrict__ bcnt,
                                             const float* __restrict__ W1,
                                             const float* __restrict__ aws,
                                             const float* __restrict__ awd,
                                             unsigned short* __restrict__ w1x) {
    __shared__ int h[NBUCK];
    int b = blockIdx.x;
    if (b < NTILE) {
        for (int i = threadIdx.x; i < NBUCK; i += 256) h[i] = 0;
        __syncthreads();
        int t0 = b * TILE;
        int t1 = (t0 + TILE < ETOT) ? t0 + TILE : ETOT;
        for (int e = t0 + threadIdx.x; e < t1; e += 256) {
            int d = (e < E) ? ei[E + e] : (e - E);
            atomicAdd(&h[d >> BSHIFT], 1);
        }
        __syncthreads();
        for (int i = threadIdx.x; i < NBUCK; i += 256) {
            int c = h[i];
            if (c) atomicAdd(&bcnt[i], c);
        }
    } else if (b < NTILE + 128) {
        int i = (b - NTILE) * 256 + threadIdx.x;
        if (i < HC * F) w1x[i] = f2bf(W1[i]);
    } else {
        int r = b - NTILE - 128;     // 0..15
        int k = threadIdx.x;
        int hh = r & 7;
        const float* aw = (r < 8) ? aws : awd;
        float acc = 0.f;
#pragma unroll
        for (int c = 0; c < 16; ++c)
            acc += aw[hh * 16 + c] * W1[(size_t)(hh * 16 + c) * F + k];
        w1x[(size_t)(128 + r) * F + k] = f2bf(acc);
    }
}

__global__ void k_bscan(const int* __restrict__ bcnt, int* __restrict__ boff,
                        int* __restrict__ bcur, int* __restrict__ off) {
    __shared__ int s[512];
    int tid = threadIdx.x;
    int v = (tid < NBUCK) ? bcnt[tid] : 0;
    s[tid] = v; __syncthreads();
    for (int ofs = 1; ofs < 512; ofs <<= 1) {
        int t = (tid >= ofs) ? s[tid - ofs] : 0;
        __syncthreads();
        s[tid] += t;
        __syncthreads();
    }
    if (tid < NBUCK) { int ex = s[tid] - v; boff[tid] = ex; bcur[tid] = ex; }
    if (tid == 0) off[N] = ETOT;
}

// ---- fused mid-pass (512 threads): part (blocks 0..NTILE-1) | gemm1 (128 rows/blk)

__global__ __launch_bounds__(512) void k_mid(const int* __restrict__ ei,
                                             int* __restrict__ bcur,
                                             unsigned int* __restrict__ pairs,
                                             const float* __restrict__ x,
                                             const unsigned short* __restrict__ w1x,
                                             unsigned char* __restrict__ h1f,
                                             float* __restrict__ as1,
                                             float* __restrict__ ad1) {
    __shared__ char smem[65536];
    if (blockIdx.x < NTILE) {
        // ---- part ----
        int* h    = (int*)smem;
        int* base = h + NBUCK;
        int t0 = blockIdx.x * TILE;
        int t1 = (t0 + TILE < ETOT) ? t0 + TILE : ETOT;
        for (int i = threadIdx.x; i < NBUCK; i += 512) h[i] = 0;
        __syncthreads();
        for (int e = t0 + threadIdx.x; e < t1; e += 512) {
            int d = (e < E) ? ei[E + e] : (e - E);
            atomicAdd(&h[d >> BSHIFT], 1);
        }
        __syncthreads();
        for (int i = threadIdx.x; i < NBUCK; i += 512) {
            int c = h[i];
            base[i] = c ? atomicAdd(&bcur[i], c) : 0;
        }
        __syncthreads();
        for (int i = threadIdx.x; i < NBUCK; i += 512) h[i] = 0;
        __syncthreads();
        for (int e = t0 + threadIdx.x; e < t1; e += 512) {
            int s, d;
            if (e < E) { s = ei[e]; d = ei[E + e]; } else { s = e - E; d = s; }
            int b = d >> BSHIFT;
            int r = atomicAdd(&h[b], 1);
            pairs[base[b] + r] = ((unsigned)s << 8) | (unsigned)(d & 255);
        }
        return;
    }
    // ---- gemm1: 8 waves x 16 rows = 128 rows per block ----
    unsigned short* Ws = (unsigned short*)smem;   // 64KB XOR-swizzled
    int bid = blockIdx.x - NTILE;
    for (int i = threadIdx.x; i < 4096; i += 512) {
        int row = i >> 5;
        int c16 = i & 31;
        u32x4 v = ((const u32x4*)w1x)[i];
        int byte = row * 512 + ((c16 * 16) ^ ((row & 7) << 4));
        *((u32x4*)((char*)Ws + byte)) = v;
    }
    __syncthreads();

    int wid = threadIdx.x >> 6, lane = threadIdx.x & 63;
    int r16 = lane & 15, g = lane >> 4;
    int m = bid * 128 + wid * 16 + r16;
    int mc = (m < N) ? m : (N - 1);
    const float* xr = x + (size_t)mc * F;
    const unsigned short* wext = w1x + (size_t)(128 + r16) * F;

    f32x4 acc[9];
#pragma unroll
    for (int nf = 0; nf < 9; ++nf) acc[nf] = (f32x4){0.f, 0.f, 0.f, 0.f};

#pragma unroll
    for (int kk = 0; kk < 8; ++kk) {
        f32x4 a0 = *((const f32x4*)(xr + kk * 32 + g * 8));
        f32x4 a1 = *((const f32x4*)(xr + kk * 32 + g * 8 + 4));
        short8 af;
#pragma unroll
        for (int j = 0; j < 4; ++j) {
            af[j]     = (short)f2bf(a0[j]);
            af[4 + j] = (short)f2bf(a1[j]);
        }
        int kbyte = kk * 64 + g * 16;
#pragma unroll
        for (int nf = 0; nf < 8; ++nf) {
            int row = nf * 16 + r16;
            int byte = row * 512 + (kbyte ^ ((row & 7) << 4));
            short8 bf = *((const short8*)((const char*)Ws + byte));
            acc[nf] = __builtin_amdgcn_mfma_f32_16x16x32_bf16(af, bf, acc[nf], 0, 0, 0);
        }
        short8 bfx = *((const short8*)(wext + kk * 32 + g * 8));
        acc[8] = __builtin_amdgcn_mfma_f32_16x16x32_bf16(af, bfx, acc[8], 0, 0, 0);
    }

    int orow = bid * 128 + wid * 16 + g * 4;
#pragma unroll
    for (int j = 0; j < 4; ++j) {
        int rr = orow + j;
        if (rr >= N) continue;
        unsigned char* dst = h1f + (size_t)rr * HC + r16;
#pragma unroll
        for (int nf = 0; nf < 8; ++nf) dst[nf * 16] = f2fp8(acc[nf][j]);
        float v = acc[8][j];
        if (r16 < 8) as1[rr * 8 + r16] = v;
        else         ad1[rr * 8 + (r16 - 8)] = v;
    }
}

// ---- bsort: per-bucket LDS counting sort; direct global scatter (L2-local) ----

__global__ __launch_bounds__(256) void k_bsort(const unsigned int* __restrict__ pairs,
                                               const int* __restrict__ bcnt,
                                               const int* __restrict__ boff,
                                               int* __restrict__ csr,
                                               int* __restrict__ off) {
    __shared__ int srcs[BCAP];           // 32KB
    __shared__ unsigned char dl[BCAP];   // 8KB
    __shared__ int hist[256];
    __shared__ int sc[256];
    int b = blockIdx.x;
    int nb = bcnt[b]; if (nb > BCAP) nb = BCAP;
    int base = boff[b];
    int dbase = b << BSHIFT;
    int ndst = (N - dbase < 256) ? (N - dbase) : 256;
    int tid = threadIdx.x;

    for (int i = tid; i < nb; i += 256) {
        unsigned int p = pairs[base + i];
        srcs[i] = (int)(p >> 8);
        dl[i] = (unsigned char)(p & 255);
    }
    hist[tid] = 0;
    __syncthreads();
    for (int i = tid; i < nb; i += 256) atomicAdd(&hist[dl[i]], 1);
    __syncthreads();
    int v = hist[tid];
    sc[tid] = v;
    __syncthreads();
    for (int ofs = 1; ofs < 256; ofs <<= 1) {
        int t = (tid >= ofs) ? sc[tid - ofs] : 0;
        __syncthreads();
        sc[tid] += t;
        __syncthreads();
    }
    int lo = sc[tid] - v;
    if (tid < ndst) off[dbase + tid] = base + lo;
    hist[tid] = lo;
    __syncthreads();
    for (int i = tid; i < nb; i += 256) {
        int r = atomicAdd(&hist[dl[i]], 1);
        csr[base + r] = srcs[i];          // scatter within contiguous 17KB region
    }
}

// ---- layer 1 aggregate + FUSED layer-2 GEMM + att scores (R16 proven, fp8) ----

__global__ __launch_bounds__(256) void k_agg1(const int* __restrict__ off,
                                              const int* __restrict__ csr,
                                              const unsigned int* __restrict__ h1w,
                                              const float* __restrict__ as1,
                                              const float* __restrict__ ad1,
                                              const float* __restrict__ b1,
                                              const float* __restrict__ W2,
                                              const float* __restrict__ aw_s2,
                                              const float* __restrict__ aw_d2,
                                              unsigned short* __restrict__ h2b,
                                              float* __restrict__ as2,
                                              float* __restrict__ ad2) {
    __shared__ float W2s[128 * 17];   // [ (q*16+c8)*17 + j ], 8.5KB
    for (int i = threadIdx.x; i < HC * NCLS; i += 256) {
        int j = i >> 7, k = i & 127;               // i = j*128 + k
        int c8 = k >> 3, q = k & 7;
        W2s[(q * 16 + c8) * 17 + j] = W2[i];
    }
    __syncthreads();

    int w = threadIdx.x >> 6, l = threadIdx.x & 63;
    int n = blockIdx.x * 4 + w;
    if (n >= N) return;
    int g  = l >> 4;            // edge slot 0..3
    int c8 = l & 15;            // channel block (8 fp8)
    int hh = c8 >> 1;           // head of this block
    unsigned int wb = (unsigned int)(c8 * 2);   // word offset into 32-word record
    int e0 = off[n], e1 = off[n + 1];
    int deg = e1 - e0;
    float adst = ad1[n * 8 + hh];
    float den = 0.f;
    float acc[8] = {0.f, 0.f, 0.f, 0.f, 0.f, 0.f, 0.f, 0.f};

    int eb = 0;
    for (; eb + 8 <= deg; eb += 8) {
        int sA = csr[e0 + eb + g];
        int sB = csr[e0 + eb + 4 + g];
        float avA = as1[sA * 8 + hh];
        float avB = as1[sB * 8 + hh];
        uint2 vA = *((const uint2*)(h1w + ((unsigned int)sA << 5) + wb));
        uint2 vB = *((const uint2*)(h1w + ((unsigned int)sB << 5) + wb));
        float aA = avA + adst; aA = fmaxf(aA, aA * NEG_SLOPE);
        float aB = avB + adst; aB = fmaxf(aB, aB * NEG_SLOPE);
        float wA = __expf(aA), wB = __expf(aB);
        den += wA + wB;
        f32x2 a01 = __builtin_amdgcn_cvt_pk_f32_fp8(vA.x, false);
        f32x2 a23 = __builtin_amdgcn_cvt_pk_f32_fp8(vA.x, true);
        f32x2 a45 = __builtin_amdgcn_cvt_pk_f32_fp8(vA.y, false);
        f32x2 a67 = __builtin_amdgcn_cvt_pk_f32_fp8(vA.y, true);
        f32x2 b01 = __builtin_amdgcn_cvt_pk_f32_fp8(vB.x, false);
        f32x2 b23 = __builtin_amdgcn_cvt_pk_f32_fp8(vB.x, true);
        f32x2 b45 = __builtin_amdgcn_cvt_pk_f32_fp8(vB.y, false);
        f32x2 b67 = __builtin_amdgcn_cvt_pk_f32_fp8(vB.y, true);
        acc[0] += wA * a01[0] + wB * b01[0];
        acc[1] += wA * a01[1] + wB * b01[1];
        acc[2] += wA * a23[0] + wB * b23[0];
        acc[3] += wA * a23[1] + wB * b23[1];
        acc[4] += wA * a45[0] + wB * b45[0];
        acc[5] += wA * a45[1] + wB * b45[1];
        acc[6] += wA * a67[0] + wB * b67[0];
        acc[7] += wA * a67[1] + wB * b67[1];
    }
    for (; eb < deg; eb += 4) {
        int slot = eb + g;
        bool ok = slot < deg;
        int s = csr[e0 + (ok ? slot : 0)];
        float aval = as1[s * 8 + hh];
        uint2 v = *((const uint2*)(h1w + ((unsigned int)s << 5) + wb));
        float al = aval + adst; al = fmaxf(al, al * NEG_SLOPE);
        float wt = ok ? __expf(al) : 0.f;
        den += wt;
        f32x2 a01 = __builtin_amdgcn_cvt_pk_f32_fp8(v.x, false);
        f32x2 a23 = __builtin_amdgcn_cvt_pk_f32_fp8(v.x, true);
        f32x2 a45 = __builtin_amdgcn_cvt_pk_f32_fp8(v.y, false);
        f32x2 a67 = __builtin_amdgcn_cvt_pk_f32_fp8(v.y, true);
        acc[0] += wt * a01[0];
        acc[1] += wt * a01[1];
        acc[2] += wt * a23[0];
        acc[3] += wt * a23[1];
        acc[4] += wt * a45[0];
        acc[5] += wt * a45[1];
        acc[6] += wt * a67[0];
        acc[7] += wt * a67[1];
    }
    // reduce over the 4 edge slots (lane bits 4,5) -> ALL lanes hold the sums
#pragma unroll
    for (int q = 0; q < 8; ++q) {
        acc[q] += __shfl_xor(acc[q], 16, 64);
        acc[q] += __shfl_xor(acc[q], 32, 64);
    }
    den += __shfl_xor(den, 16, 64);
    den += __shfl_xor(den, 32, 64);

    // ---- fused epilogue (all 64 lanes) ----
    float inv = 1.f / (den + 1e-16f);
    float v8[8];
#pragma unroll
    for (int q = 0; q < 8; ++q) {
        float v = acc[q] * inv + b1[c8 * 8 + q];
        v8[q] = (v > 0.f) ? v : (__expf(v) - 1.f);   // ELU: out1 channel c8*8+q
    }
    float p0 = 0.f, p1 = 0.f, p2 = 0.f, p3 = 0.f;
#pragma unroll
    for (int q = 0; q < 8; ++q) {
        const float* wr = &W2s[(q * 16 + c8) * 17 + g * 4];
        p0 += v8[q] * wr[0];
        p1 += v8[q] * wr[1];
        p2 += v8[q] * wr[2];
        p3 += v8[q] * wr[3];
    }
#pragma unroll
    for (int msk = 8; msk >= 1; msk >>= 1) {
        p0 += __shfl_xor(p0, msk, 64);
        p1 += __shfl_xor(p1, msk, 64);
        p2 += __shfl_xor(p2, msk, 64);
        p3 += __shfl_xor(p3, msk, 64);
    }
    float sa = p0 * aw_s2[g * 4] + p1 * aw_s2[g * 4 + 1]
             + p2 * aw_s2[g * 4 + 2] + p3 * aw_s2[g * 4 + 3];
    float da = p0 * aw_d2[g * 4] + p1 * aw_d2[g * 4 + 1]
             + p2 * aw_d2[g * 4 + 2] + p3 * aw_d2[g * 4 + 3];
    sa += __shfl_xor(sa, 16, 64); sa += __shfl_xor(sa, 32, 64);
    da += __shfl_xor(da, 16, 64); da += __shfl_xor(da, 32, 64);
    if (l == 0) { as2[n] = sa; ad2[n] = da; }
    if (c8 < 4) {
        float h2v = p0;
        h2v = (c8 == 1) ? p1 : h2v;
        h2v = (c8 == 2) ? p2 : h2v;
        h2v = (c8 == 3) ? p3 : h2v;
        h2b[(size_t)n * NCLS + g * 4 + c8] = f2bf(h2v);
    }
}

// ---------------- layer 2 aggregate (bf16 gather, unrolled x4) + log_softmax ----

__global__ __launch_bounds__(256) void k_agg2(const int* __restrict__ off,
                                              const int* __restrict__ csr,
                                              const float* __restrict__ as2,
                                              const float* __restrict__ ad2,
                                              const unsigned short* __restrict__ h2b,
                                              const float* __restrict__ b2,
                                              float* __restrict__ outp) {
    int gpos = threadIdx.x >> 4, c = threadIdx.x & 15;
    int n = blockIdx.x * 16 + gpos;
    if (n >= N) return;
    int e0 = off[n], e1 = off[n + 1];
    float adst = ad2[n];
    float den = 0.f, acc = 0.f;
    int e = e0;
    for (; e + 4 <= e1; e += 4) {
        int s0 = csr[e], s1 = csr[e + 1], s2 = csr[e + 2], s3 = csr[e + 3];
        float x0 = as2[s0], x1 = as2[s1], x2 = as2[s2], x3 = as2[s3];
        unsigned short m0 = h2b[s0 * NCLS + c], m1 = h2b[s1 * NCLS + c];
        unsigned short m2 = h2b[s2 * NCLS + c], m3 = h2b[s3 * NCLS + c];
        float a0 = x0 + adst; a0 = fmaxf(a0, a0 * NEG_SLOPE);
        float a1 = x1 + adst; a1 = fmaxf(a1, a1 * NEG_SLOPE);
        float a2 = x2 + adst; a2 = fmaxf(a2, a2 * NEG_SLOPE);
        float a3 = x3 + adst; a3 = fmaxf(a3, a3 * NEG_SLOPE);
        float w0 = __expf(a0), w1 = __expf(a1), w2 = __expf(a2), w3 = __expf(a3);
        den += (w0 + w1) + (w2 + w3);
        acc += w0 * bf2f(m0) + w1 * bf2f(m1) + w2 * bf2f(m2) + w3 * bf2f(m3);
    }
    for (; e < e1; ++e) {
        int s = csr[e];
        float al = as2[s] + adst;
        al = fmaxf(al, al * NEG_SLOPE);
        float wt = __expf(al);
        den += wt;
        acc += wt * bf2f(h2b[s * NCLS + c]);
    }
    float v = acc / (den + 1e-16f) + b2[c];
    float mx = v;
#pragma unroll
    for (int msk = 8; msk >= 1; msk >>= 1) mx = fmaxf(mx, __shfl_xor(mx, msk, 64));
    float ex = __expf(v - mx), se = ex;
#pragma unroll
    for (int msk = 8; msk >= 1; msk >>= 1) se += __shfl_xor(se, msk, 64);
    outp[n * NCLS + c] = v - mx - __logf(se);
}

// ---------------- launch ----------------

extern "C" void kernel_launch(void* const* d_in, const int* in_sizes, int n_in,
                              void* d_out, int out_size, void* d_ws, size_t ws_size,
                              hipStream_t stream) {
    const float* x        = (const float*)d_in[0];
    const int*   ei       = (const int*)d_in[1];
    const float* W1       = (const float*)d_in[2];
    const float* att_src1 = (const float*)d_in[3];
    const float* att_dst1 = (const float*)d_in[4];
    const float* b1       = (const float*)d_in[5];
    const float* W2       = (const float*)d_in[6];
    const float* att_src2 = (const float*)d_in[7];
    const float* att_dst2 = (const float*)d_in[8];
    const float* b2       = (const float*)d_in[9];
    float* outp = (float*)d_out;

    char* p = (char*)d_ws;
    unsigned char* h1f    = (unsigned char*)p;  p += (size_t)N * HC;       // 12.8MB fp8
    unsigned short* h2b   = (unsigned short*)p; p += (size_t)N * NCLS * 2; // 3.2MB
    float* as1  = (float*)p; p += (size_t)N * H * 4;                       // 3.2MB
    float* ad1  = (float*)p; p += (size_t)N * H * 4;                       // 3.2MB
    float* as2  = (float*)p; p += (size_t)N * 4;
    float* ad2  = (float*)p; p += (size_t)N * 4;
    unsigned short* w1x = (unsigned short*)p; p += (size_t)144 * F * 2;    // 73.7KB
    unsigned int* pairs = (unsigned int*)p; p += (size_t)ETOT * 4;         // 6.8MB
    int* csr    = (int*)p;   p += (size_t)ETOT * 4;
    int* off    = (int*)p;   p += (size_t)(N + 1) * 4;
    int* bcnt   = (int*)p;   p += (size_t)NBUCK * 4;
    int* boff   = (int*)p;   p += (size_t)NBUCK * 4;
    int* bcur   = (int*)p;   p += (size_t)NBUCK * 4;

    hipMemsetAsync(bcnt, 0, (size_t)NBUCK * 4, stream);

    k_pre<<<NTILE + 128 + 16, 256, 0, stream>>>(ei, bcnt, W1, att_src1, att_dst1, w1x);
    k_bscan<<<1, 512, 0, stream>>>(bcnt, boff, bcur, off);
    k_mid<<<NTILE + (N + 127) / 128, 512, 0, stream>>>(ei, bcur, pairs,
                                                       x, w1x, h1f, as1, ad1);
    k_bsort<<<NBUCK, 256, 0, stream>>>(pairs, bcnt, boff, csr, off);

    k_agg1<<<(N + 3) / 4, 256, 0, stream>>>(off, csr, (const unsigned int*)h1f,
                                            as1, ad1, b1, W2, att_src2, att_dst2,
                                            h2b, as2, ad2);

    k_agg2<<<(N + 15) / 16, 256, 0, stream>>>(off, csr, as2, ad2, h2b, b2, outp);
}

// Round 19
// 213.485 us; speedup vs baseline: 1.9105x; 1.0026x over previous
//
#include <hip/hip_runtime.h>
#include <hip/hip_bf16.h>
#include <stdint.h>

constexpr int N     = 100000;
constexpr int E     = 1600000;
constexpr int ETOT  = E + N;
constexpr int F     = 256;
constexpr int H     = 8;
constexpr int C     = 16;
constexpr int HC    = H * C;      // 128
constexpr int NCLS  = 16;
constexpr float NEG_SLOPE = 0.2f;

constexpr int BSHIFT = 8;                       // 256 dsts per bucket
constexpr int NBUCK  = (N + 255) >> BSHIFT;     // 391
constexpr int BCAP   = 8192;
constexpr int TILE   = 16384;
constexpr int NTILE  = (ETOT + TILE - 1) / TILE;   // 104

typedef __attribute__((ext_vector_type(8))) short short8;
typedef __attribute__((ext_vector_type(4))) float f32x4;
typedef __attribute__((ext_vector_type(2))) float f32x2;
typedef __attribute__((ext_vector_type(4))) unsigned int u32x4;

__device__ inline unsigned short f2bf(float f) {
    union { float f; unsigned int u; } v{f};
    unsigned int r = v.u + 0x7FFF + ((v.u >> 16) & 1);   // RNE
    return (unsigned short)(r >> 16);
}
__device__ inline float bf2f(unsigned short s) {
    union { unsigned int u; float f; } v{(unsigned int)s << 16};
    return v.f;
}
__device__ inline unsigned char f2fp8(float v) {
    return (unsigned char)(__builtin_amdgcn_cvt_pk_fp8_f32(v, v, 0, false) & 0xff);
}

// ---- fused pre-pass: bhist (blocks 0..NTILE-1) | w1cast (next 128) | wext (next 16)

__global__ __launch_bounds__(256) void k_pre(const int* __restrict__ ei,
                                             int* __restrict__ bcnt,
                                             const float* __restrict__ W1,
                                             const float* __restrict__ aws,
                                             const float* __restrict__ awd,
                                             unsigned short* __restrict__ w1x) {
    __shared__ int h[NBUCK];
    int b = blockIdx.x;
    if (b < NTILE) {
        for (int i = threadIdx.x; i < NBUCK; i += 256) h[i] = 0;
        __syncthreads();
        int t0 = b * TILE;
        int t1 = (t0 + TILE < ETOT) ? t0 + TILE : ETOT;
        for (int e = t0 + threadIdx.x; e < t1; e += 256) {
            int d = (e < E) ? ei[E + e] : (e - E);
            atomicAdd(&h[d >> BSHIFT], 1);
        }
        __syncthreads();
        for (int i = threadIdx.x; i < NBUCK; i += 256) {
            int c = h[i];
            if (c) atomicAdd(&bcnt[i], c);
        }
    } else if (b < NTILE + 128) {
        int i = (b - NTILE) * 256 + threadIdx.x;
        if (i < HC * F) w1x[i] = f2bf(W1[i]);
    } else {
        int r = b - NTILE - 128;     // 0..15
        int k = threadIdx.x;
        int hh = r & 7;
        const float* aw = (r < 8) ? aws : awd;
        float acc = 0.f;
#pragma unroll
        for (int c = 0; c < 16; ++c)
            acc += aw[hh * 16 + c] * W1[(size_t)(hh * 16 + c) * F + k];
        w1x[(size_t)(128 + r) * F + k] = f2bf(acc);
    }
}

__global__ void k_bscan(const int* __restrict__ bcnt, int* __restrict__ boff,
                        int* __restrict__ bcur, int* __restrict__ off) {
    __shared__ int s[512];
    int tid = threadIdx.x;
    int v = (tid < NBUCK) ? bcnt[tid] : 0;
    s[tid] = v; __syncthreads();
    for (int ofs = 1; ofs < 512; ofs <<= 1) {
        int t = (tid >= ofs) ? s[tid - ofs] : 0;
        __syncthreads();
        s[tid] += t;
        __syncthreads();
    }
    if (tid < NBUCK) { int ex = s[tid] - v; boff[tid] = ex; bcur[tid] = ex; }
    if (tid == 0) off[N] = ETOT;
}

// ---- fused mid-pass (512 threads): part (blocks 0..NTILE-1) | gemm1 (128 rows/blk)

__global__ __launch_bounds__(512) void k_mid(const int* __restrict__ ei,
                                             int* __restrict__ bcur,
                                             unsigned int* __restrict__ pairs,
                                             const float* __restrict__ x,
                                             const unsigned short* __restrict__ w1x,
                                             unsigned char* __restrict__ h1f,
                                             float* __restrict__ as1,
                                             float* __restrict__ ad1) {
    __shared__ char smem[65536];
    if (blockIdx.x < NTILE) {
        // ---- part ----
        int* h    = (int*)smem;
        int* base = h + NBUCK;
        int t0 = blockIdx.x * TILE;
        int t1 = (t0 + TILE < ETOT) ? t0 + TILE : ETOT;
        for (int i = threadIdx.x; i < NBUCK; i += 512) h[i] = 0;
        __syncthreads();
        for (int e = t0 + threadIdx.x; e < t1; e += 512) {
            int d = (e < E) ? ei[E + e] : (e - E);
            atomicAdd(&h[d >> BSHIFT], 1);
        }
        __syncthreads();
        for (int i = threadIdx.x; i < NBUCK; i += 512) {
            int c = h[i];
            base[i] = c ? atomicAdd(&bcur[i], c) : 0;
        }
        __syncthreads();
        for (int i = threadIdx.x; i < NBUCK; i += 512) h[i] = 0;
        __syncthreads();
        for (int e = t0 + threadIdx.x; e < t1; e += 512) {
            int s, d;
            if (e < E) { s = ei[e]; d = ei[E + e]; } else { s = e - E; d = s; }
            int b = d >> BSHIFT;
            int r = atomicAdd(&h[b], 1);
            pairs[base[b] + r] = ((unsigned)s << 8) | (unsigned)(d & 255);
        }
        return;
    }
    // ---- gemm1: 8 waves x 16 rows = 128 rows per block ----
    unsigned short* Ws = (unsigned short*)smem;   // 64KB XOR-swizzled
    int bid = blockIdx.x - NTILE;
    for (int i = threadIdx.x; i < 4096; i += 512) {
        int row = i >> 5;
        int c16 = i & 31;
        u32x4 v = ((const u32x4*)w1x)[i];
        int byte = row * 512 + ((c16 * 16) ^ ((row & 7) << 4));
        *((u32x4*)((char*)Ws + byte)) = v;
    }
    __syncthreads();

    int wid = threadIdx.x >> 6, lane = threadIdx.x & 63;
    int r16 = lane & 15, g = lane >> 4;
    int m = bid * 128 + wid * 16 + r16;
    int mc = (m < N) ? m : (N - 1);
    const float* xr = x + (size_t)mc * F;
    const unsigned short* wext = w1x + (size_t)(128 + r16) * F;

    f32x4 acc[9];
#pragma unroll
    for (int nf = 0; nf < 9; ++nf) acc[nf] = (f32x4){0.f, 0.f, 0.f, 0.f};

#pragma unroll
    for (int kk = 0; kk < 8; ++kk) {
        f32x4 a0 = *((const f32x4*)(xr + kk * 32 + g * 8));
        f32x4 a1 = *((const f32x4*)(xr + kk * 32 + g * 8 + 4));
        short8 af;
#pragma unroll
        for (int j = 0; j < 4; ++j) {
            af[j]     = (short)f2bf(a0[j]);
            af[4 + j] = (short)f2bf(a1[j]);
        }
        int kbyte = kk * 64 + g * 16;
#pragma unroll
        for (int nf = 0; nf < 8; ++nf) {
            int row = nf * 16 + r16;
            int byte = row * 512 + (kbyte ^ ((row & 7) << 4));
            short8 bf = *((const short8*)((const char*)Ws + byte));
            acc[nf] = __builtin_amdgcn_mfma_f32_16x16x32_bf16(af, bf, acc[nf], 0, 0, 0);
        }
        short8 bfx = *((const short8*)(wext + kk * 32 + g * 8));
        acc[8] = __builtin_amdgcn_mfma_f32_16x16x32_bf16(af, bfx, acc[8], 0, 0, 0);
    }

    int orow = bid * 128 + wid * 16 + g * 4;
#pragma unroll
    for (int j = 0; j < 4; ++j) {
        int rr = orow + j;
        if (rr >= N) continue;
        unsigned char* dst = h1f + (size_t)rr * HC + r16;
#pragma unroll
        for (int nf = 0; nf < 8; ++nf) dst[nf * 16] = f2fp8(acc[nf][j]);
        float v = acc[8][j];
        if (r16 < 8) as1[rr * 8 + r16] = v;
        else         ad1[rr * 8 + (r16 - 8)] = v;
    }
}

// ---- bsort: per-bucket LDS counting sort; direct global scatter (L2-local) ----

__global__ __launch_bounds__(256) void k_bsort(const unsigned int* __restrict__ pairs,
                                               const int* __restrict__ bcnt,
                                               const int* __restrict__ boff,
                                               int* __restrict__ csr,
                                               int* __restrict__ off) {
    __shared__ int srcs[BCAP];           // 32KB
    __shared__ unsigned char dl[BCAP];   // 8KB
    __shared__ int hist[256];
    __shared__ int sc[256];
    int b = blockIdx.x;
    int nb = bcnt[b]; if (nb > BCAP) nb = BCAP;
    int base = boff[b];
    int dbase = b << BSHIFT;
    int ndst = (N - dbase < 256) ? (N - dbase) : 256;
    int tid = threadIdx.x;

    for (int i = tid; i < nb; i += 256) {
        unsigned int p = pairs[base + i];
        srcs[i] = (int)(p >> 8);
        dl[i] = (unsigned char)(p & 255);
    }
    hist[tid] = 0;
    __syncthreads();
    for (int i = tid; i < nb; i += 256) atomicAdd(&hist[dl[i]], 1);
    __syncthreads();
    int v = hist[tid];
    sc[tid] = v;
    __syncthreads();
    for (int ofs = 1; ofs < 256; ofs <<= 1) {
        int t = (tid >= ofs) ? sc[tid - ofs] : 0;
        __syncthreads();
        sc[tid] += t;
        __syncthreads();
    }
    int lo = sc[tid] - v;
    if (tid < ndst) off[dbase + tid] = base + lo;
    hist[tid] = lo;
    __syncthreads();
    for (int i = tid; i < nb; i += 256) {
        int r = atomicAdd(&hist[dl[i]], 1);
        csr[base + r] = srcs[i];          // scatter within contiguous 17KB region
    }
}

// ---- layer 1 aggregate + fused layer-2 GEMM: grid-stride, reg fragments, NO LDS ----
// 4 slots (g=l>>4) x 16 lanes (c8=l&15, 8 fp8 channels); packed f32x2 edge math.

__global__ __launch_bounds__(256) void k_agg1(const int* __restrict__ off,
                                              const int* __restrict__ csr,
                                              const unsigned int* __restrict__ h1w,
                                              const float* __restrict__ as1,
                                              const float* __restrict__ ad1,
                                              const float* __restrict__ b1,
                                              const float* __restrict__ W2,
                                              const float* __restrict__ aw_s2,
                                              const float* __restrict__ aw_d2,
                                              unsigned short* __restrict__ h2b,
                                              float* __restrict__ as2,
                                              float* __restrict__ ad2) {
    int w = threadIdx.x >> 6, l = threadIdx.x & 63;
    int g  = l >> 4;            // edge slot 0..3 / class group
    int c8 = l & 15;            // channel block (8 fp8)
    int hh = c8 >> 1;           // head of this block
    unsigned int wb = (unsigned int)(c8 * 2);   // word offset into 32-word record

    // one-time register fragments (global reads; W2 8KB + b1/aw -> L1/L2-hot)
    float w2f[32];
#pragma unroll
    for (int q = 0; q < 8; ++q)
#pragma unroll
        for (int j = 0; j < 4; ++j)
            w2f[q * 4 + j] = W2[(size_t)(g * 4 + j) * HC + c8 * 8 + q];
    float b1f[8];
#pragma unroll
    for (int q = 0; q < 8; ++q) b1f[q] = b1[c8 * 8 + q];
    float awsf[4], awdf[4];
#pragma unroll
    for (int j = 0; j < 4; ++j) {
        awsf[j] = aw_s2[g * 4 + j];
        awdf[j] = aw_d2[g * 4 + j];
    }

    for (int n = blockIdx.x * 4 + w; n < N; n += gridDim.x * 4) {
        int e0 = off[n], e1 = off[n + 1];
        int deg = e1 - e0;
        float adst = ad1[n * 8 + hh];
        float den = 0.f;
        f32x2 acc0 = {0.f, 0.f}, acc1 = {0.f, 0.f};
        f32x2 acc2 = {0.f, 0.f}, acc3 = {0.f, 0.f};

        int eb = 0;
        for (; eb + 8 <= deg; eb += 8) {
            int sA = csr[e0 + eb + g];
            int sB = csr[e0 + eb + 4 + g];
            float avA = as1[sA * 8 + hh];
            float avB = as1[sB * 8 + hh];
            uint2 vA = *((const uint2*)(h1w + ((unsigned int)sA << 5) + wb));
            uint2 vB = *((const uint2*)(h1w + ((unsigned int)sB << 5) + wb));
            float aA = avA + adst; aA = fmaxf(aA, aA * NEG_SLOPE);
            float aB = avB + adst; aB = fmaxf(aB, aB * NEG_SLOPE);
            float wA = __expf(aA), wB = __expf(aB);
            den += wA + wB;
            f32x2 wA2 = {wA, wA}, wB2 = {wB, wB};
            acc0 += wA2 * __builtin_amdgcn_cvt_pk_f32_fp8(vA.x, false)
                  + wB2 * __builtin_amdgcn_cvt_pk_f32_fp8(vB.x, false);
            acc1 += wA2 * __builtin_amdgcn_cvt_pk_f32_fp8(vA.x, true)
                  + wB2 * __builtin_amdgcn_cvt_pk_f32_fp8(vB.x, true);
            acc2 += wA2 * __builtin_amdgcn_cvt_pk_f32_fp8(vA.y, false)
                  + wB2 * __builtin_amdgcn_cvt_pk_f32_fp8(vB.y, false);
            acc3 += wA2 * __builtin_amdgcn_cvt_pk_f32_fp8(vA.y, true)
                  + wB2 * __builtin_amdgcn_cvt_pk_f32_fp8(vB.y, true);
        }
        for (; eb < deg; eb += 4) {
            int slot = eb + g;
            bool ok = slot < deg;
            int s = csr[e0 + (ok ? slot : 0)];
            float aval = as1[s * 8 + hh];
            uint2 v = *((const uint2*)(h1w + ((unsigned int)s << 5) + wb));
            float al = aval + adst; al = fmaxf(al, al * NEG_SLOPE);
            float wt = ok ? __expf(al) : 0.f;
            den += wt;
            f32x2 wt2 = {wt, wt};
            acc0 += wt2 * __builtin_amdgcn_cvt_pk_f32_fp8(v.x, false);
            acc1 += wt2 * __builtin_amdgcn_cvt_pk_f32_fp8(v.x, true);
            acc2 += wt2 * __builtin_amdgcn_cvt_pk_f32_fp8(v.y, false);
            acc3 += wt2 * __builtin_amdgcn_cvt_pk_f32_fp8(v.y, true);
        }
        // reduce over the 4 edge slots (lane bits 4,5) -> ALL lanes hold sums
        float acc[8] = {acc0[0], acc0[1], acc1[0], acc1[1],
                        acc2[0], acc2[1], acc3[0], acc3[1]};
#pragma unroll
        for (int q = 0; q < 8; ++q) {
            acc[q] += __shfl_xor(acc[q], 16, 64);
            acc[q] += __shfl_xor(acc[q], 32, 64);
        }
        den += __shfl_xor(den, 16, 64);
        den += __shfl_xor(den, 32, 64);

        // ---- fused epilogue (all 64 lanes, pure registers) ----
        float inv = 1.f / (den + 1e-16f);
        float p0 = 0.f, p1 = 0.f, p2 = 0.f, p3 = 0.f;
#pragma unroll
        for (int q = 0; q < 8; ++q) {
            float v = acc[q] * inv + b1f[q];
            v = (v > 0.f) ? v : (__expf(v) - 1.f);   // ELU
            p0 += v * w2f[q * 4 + 0];
            p1 += v * w2f[q * 4 + 1];
            p2 += v * w2f[q * 4 + 2];
            p3 += v * w2f[q * 4 + 3];
        }
#pragma unroll
        for (int msk = 8; msk >= 1; msk >>= 1) {
            p0 += __shfl_xor(p0, msk, 64);
            p1 += __shfl_xor(p1, msk, 64);
            p2 += __shfl_xor(p2, msk, 64);
            p3 += __shfl_xor(p3, msk, 64);
        }
        float sa = p0 * awsf[0] + p1 * awsf[1] + p2 * awsf[2] + p3 * awsf[3];
        float da = p0 * awdf[0] + p1 * awdf[1] + p2 * awdf[2] + p3 * awdf[3];
        sa += __shfl_xor(sa, 16, 64); sa += __shfl_xor(sa, 32, 64);
        da += __shfl_xor(da, 16, 64); da += __shfl_xor(da, 32, 64);
        if (l == 0) { as2[n] = sa; ad2[n] = da; }
        if (c8 == 0) {
            uint2 pk;
            pk.x = ((unsigned int)f2bf(p1) << 16) | f2bf(p0);
            pk.y = ((unsigned int)f2bf(p3) << 16) | f2bf(p2);
            *((uint2*)(h2b + (size_t)n * NCLS + g * 4)) = pk;
        }
    }
}

// ---------------- layer 2 aggregate (bf16 gather, unrolled x4) + log_softmax ----

__global__ __launch_bounds__(256) void k_agg2(const int* __restrict__ off,
                                              const int* __restrict__ csr,
                                              const float* __restrict__ as2,
                                              const float* __restrict__ ad2,
                                              const unsigned short* __restrict__ h2b,
                                              const float* __restrict__ b2,
                                              float* __restrict__ outp) {
    int gpos = threadIdx.x >> 4, c = threadIdx.x & 15;
    int n = blockIdx.x * 16 + gpos;
    if (n >= N) return;
    int e0 = off[n], e1 = off[n + 1];
    float adst = ad2[n];
    float den = 0.f, acc = 0.f;
    int e = e0;
    for (; e + 4 <= e1; e += 4) {
        int s0 = csr[e], s1 = csr[e + 1], s2 = csr[e + 2], s3 = csr[e + 3];
        float x0 = as2[s0], x1 = as2[s1], x2 = as2[s2], x3 = as2[s3];
        unsigned short m0 = h2b[s0 * NCLS + c], m1 = h2b[s1 * NCLS + c];
        unsigned short m2 = h2b[s2 * NCLS + c], m3 = h2b[s3 * NCLS + c];
        float a0 = x0 + adst; a0 = fmaxf(a0, a0 * NEG_SLOPE);
        float a1 = x1 + adst; a1 = fmaxf(a1, a1 * NEG_SLOPE);
        float a2 = x2 + adst; a2 = fmaxf(a2, a2 * NEG_SLOPE);
        float a3 = x3 + adst; a3 = fmaxf(a3, a3 * NEG_SLOPE);
        float w0 = __expf(a0), w1 = __expf(a1), w2 = __expf(a2), w3 = __expf(a3);
        den += (w0 + w1) + (w2 + w3);
        acc += w0 * bf2f(m0) + w1 * bf2f(m1) + w2 * bf2f(m2) + w3 * bf2f(m3);
    }
    for (; e < e1; ++e) {
        int s = csr[e];
        float al = as2[s] + adst;
        al = fmaxf(al, al * NEG_SLOPE);
        float wt = __expf(al);
        den += wt;
        acc += wt * bf2f(h2b[s * NCLS + c]);
    }
    float v = acc / (den + 1e-16f) + b2[c];
    float mx = v;
#pragma unroll
    for (int msk = 8; msk >= 1; msk >>= 1) mx = fmaxf(mx, __shfl_xor(mx, msk, 64));
    float ex = __expf(v - mx), se = ex;
#pragma unroll
    for (int msk = 8; msk >= 1; msk >>= 1) se += __shfl_xor(se, msk, 64);
    outp[n * NCLS + c] = v - mx - __logf(se);
}

// ---------------- launch ----------------

extern "C" void kernel_launch(void* const* d_in, const int* in_sizes, int n_in,
                              void* d_out, int out_size, void* d_ws, size_t ws_size,
                              hipStream_t stream) {
    const float* x        = (const float*)d_in[0];
    const int*   ei       = (const int*)d_in[1];
    const float* W1       = (const float*)d_in[2];
    const float* att_src1 = (const float*)d_in[3];
    const float* att_dst1 = (const float*)d_in[4];
    const float* b1       = (const float*)d_in[5];
    const float* W2       = (const float*)d_in[6];
    const float* att_src2 = (const float*)d_in[7];
    const float* att_dst2 = (const float*)d_in[8];
    const float* b2       = (const float*)d_in[9];
    float* outp = (float*)d_out;

    char* p = (char*)d_ws;
    unsigned char* h1f    = (unsigned char*)p;  p += (size_t)N * HC;       // 12.8MB fp8
    unsigned short* h2b   = (unsigned short*)p; p += (size_t)N * NCLS * 2; // 3.2MB
    float* as1  = (float*)p; p += (size_t)N * H * 4;                       // 3.2MB
    float* ad1  = (float*)p; p += (size_t)N * H * 4;                       // 3.2MB
    float* as2  = (float*)p; p += (size_t)N * 4;
    float* ad2  = (float*)p; p += (size_t)N * 4;
    unsigned short* w1x = (unsigned short*)p; p += (size_t)144 * F * 2;    // 73.7KB
    unsigned int* pairs = (unsigned int*)p; p += (size_t)ETOT * 4;         // 6.8MB
    int* csr    = (int*)p;   p += (size_t)ETOT * 4;
    int* off    = (int*)p;   p += (size_t)(N + 1) * 4;
    int* bcnt   = (int*)p;   p += (size_t)NBUCK * 4;
    int* boff   = (int*)p;   p += (size_t)NBUCK * 4;
    int* bcur   = (int*)p;   p += (size_t)NBUCK * 4;

    hipMemsetAsync(bcnt, 0, (size_t)NBUCK * 4, stream);

    k_pre<<<NTILE + 128 + 16, 256, 0, stream>>>(ei, bcnt, W1, att_src1, att_dst1, w1x);
    k_bscan<<<1, 512, 0, stream>>>(bcnt, boff, bcur, off);
    k_mid<<<NTILE + (N + 127) / 128, 512, 0, stream>>>(ei, bcur, pairs,
                                                       x, w1x, h1f, as1, ad1);
    k_bsort<<<NBUCK, 256, 0, stream>>>(pairs, bcnt, boff, csr, off);

    k_agg1<<<4096, 256, 0, stream>>>(off, csr, (const unsigned int*)h1f,
                                     as1, ad1, b1, W2, att_src2, att_dst2,
                                     h2b, as2, ad2);

    k_agg2<<<(N + 15) / 16, 256, 0, stream>>>(off, csr, as2, ad2, h2b, b2, outp);
}